// Round 1
// baseline (4686.299 us; speedup 1.0000x reference)
//
#include <hip/hip_runtime.h>
#include <math.h>

#define N_C 100000
#define HD 128

// ------------------------------------------------------------------
// small prep kernels
// ------------------------------------------------------------------
__global__ void count_kernel(const int* __restrict__ ei, int* __restrict__ cnt, int E) {
  int e = blockIdx.x * 256 + threadIdx.x;
  if (e < E) atomicAdd(&cnt[ei[E + e]], 1);
}

__global__ void inv_kernel(const int* __restrict__ cnt, float* __restrict__ inv, int n) {
  int i = blockIdx.x * 256 + threadIdx.x;
  if (i < n) inv[i] = 1.0f / fmaxf((float)cnt[i], 1.0f);
}

__global__ void add3_kernel(const float* __restrict__ a, const float* __restrict__ b,
                            const float* __restrict__ c, float* __restrict__ o, int n) {
  int i = blockIdx.x * 256 + threadIdx.x;
  if (i < n) o[i] = a[i] + b[i] + c[i];
}

// ------------------------------------------------------------------
// scaled scatter-add: out[dst] += y[src] * inv_cnt[dst]   (H=128)
// 32 lanes per edge (float4 each), 8 edges per 256-thread block
// ------------------------------------------------------------------
__global__ __launch_bounds__(256) void scatter_kernel(
    const float* __restrict__ y, const int* __restrict__ ei,
    const float* __restrict__ inv, float* __restrict__ out, int E) {
  int e = blockIdx.x * 8 + (threadIdx.x >> 5);
  if (e >= E) return;
  int lane = threadIdx.x & 31;
  int src = ei[e];
  int dst = ei[E + e];
  float s = inv[dst];
  float4 v = ((const float4*)(y + (size_t)src * HD))[lane];
  float* o = out + (size_t)dst * HD + lane * 4;
  atomicAdd(o + 0, v.x * s);
  atomicAdd(o + 1, v.y * s);
  atomicAdd(o + 2, v.z * s);
  atomicAdd(o + 3, v.w * s);
}

// ------------------------------------------------------------------
// fp32 tiled GEMM: C0 = act(A)@B0 [, C1 = act(A)@B1 + bias1]
// A: M x K row-major, B: K x 128 row-major, C: M x 128
// BM=64, BK=16, 256 threads, thread tile 4x8 (per B)
// ------------------------------------------------------------------
template <bool DUAL, bool RELUA>
__global__ __launch_bounds__(256) void gemm_kernel(
    const float* __restrict__ A, int K, int M,
    const float* __restrict__ B0, const float* __restrict__ B1,
    float* __restrict__ C0, float* __restrict__ C1,
    const float* __restrict__ bias1) {
  constexpr int BM = 64, BK = 16;
  __shared__ float As[BK][BM + 4];
  __shared__ float Bs0[BK][128];
  __shared__ float Bs1[DUAL ? BK : 1][DUAL ? 128 : 4];

  const int t = threadIdx.x;
  const int m0 = blockIdx.x * BM;
  const int ty = t >> 4;        // 0..15 -> rows ty*4..ty*4+3
  const int tx = t & 15;        // 0..15 -> cols tx*4 and 64+tx*4
  const int arow = t >> 2;      // 0..63
  const int acol = (t & 3) * 4; // 0,4,8,12
  const int brow = t >> 5;      // 0..7
  const int bcol = (t & 31) * 4;

  float acc0[4][8];
  float acc1[DUAL ? 4 : 1][DUAL ? 8 : 1];
#pragma unroll
  for (int i = 0; i < 4; ++i)
#pragma unroll
    for (int j = 0; j < 8; ++j) acc0[i][j] = 0.f;
  if constexpr (DUAL) {
#pragma unroll
    for (int i = 0; i < 4; ++i)
#pragma unroll
      for (int j = 0; j < 8; ++j) acc1[i][j] = 0.f;
  }

  const int gr_a = m0 + arow;
  const bool a_ok = gr_a < M;
  const float* Arow = A + (size_t)gr_a * K;

  for (int k0 = 0; k0 < K; k0 += BK) {
    float4 av = make_float4(0.f, 0.f, 0.f, 0.f);
    if (a_ok) av = *(const float4*)(Arow + k0 + acol);
    if (RELUA) {
      av.x = fmaxf(av.x, 0.f); av.y = fmaxf(av.y, 0.f);
      av.z = fmaxf(av.z, 0.f); av.w = fmaxf(av.w, 0.f);
    }
    As[acol + 0][arow] = av.x;
    As[acol + 1][arow] = av.y;
    As[acol + 2][arow] = av.z;
    As[acol + 3][arow] = av.w;
#pragma unroll
    for (int r = 0; r < BK; r += 8) {
      *(float4*)&Bs0[r + brow][bcol] =
          *(const float4*)(B0 + (size_t)(k0 + r + brow) * 128 + bcol);
      if constexpr (DUAL) {
        *(float4*)&Bs1[r + brow][bcol] =
            *(const float4*)(B1 + (size_t)(k0 + r + brow) * 128 + bcol);
      }
    }
    __syncthreads();
#pragma unroll
    for (int kk = 0; kk < BK; ++kk) {
      float4 af = *(const float4*)&As[kk][ty * 4];
      float a[4] = {af.x, af.y, af.z, af.w};
      float b0[8];
      *(float4*)&b0[0] = *(const float4*)&Bs0[kk][tx * 4];
      *(float4*)&b0[4] = *(const float4*)&Bs0[kk][64 + tx * 4];
#pragma unroll
      for (int i = 0; i < 4; ++i)
#pragma unroll
        for (int j = 0; j < 8; ++j) acc0[i][j] += a[i] * b0[j];
      if constexpr (DUAL) {
        float b1[8];
        *(float4*)&b1[0] = *(const float4*)&Bs1[kk][tx * 4];
        *(float4*)&b1[4] = *(const float4*)&Bs1[kk][64 + tx * 4];
#pragma unroll
        for (int i = 0; i < 4; ++i)
#pragma unroll
          for (int j = 0; j < 8; ++j) acc1[i][j] += a[i] * b1[j];
      }
    }
    __syncthreads();
  }

  float bA[4] = {0.f, 0.f, 0.f, 0.f}, bB[4] = {0.f, 0.f, 0.f, 0.f};
  if constexpr (DUAL) {
#pragma unroll
    for (int j = 0; j < 4; ++j) {
      bA[j] = bias1[tx * 4 + j];
      bB[j] = bias1[64 + tx * 4 + j];
    }
  }
#pragma unroll
  for (int i = 0; i < 4; ++i) {
    int gr = m0 + ty * 4 + i;
    if (gr < M) {
      float4 o;
      o = make_float4(acc0[i][0], acc0[i][1], acc0[i][2], acc0[i][3]);
      *(float4*)(C0 + (size_t)gr * 128 + tx * 4) = o;
      o = make_float4(acc0[i][4], acc0[i][5], acc0[i][6], acc0[i][7]);
      *(float4*)(C0 + (size_t)gr * 128 + 64 + tx * 4) = o;
      if constexpr (DUAL) {
        o = make_float4(acc1[i][0] + bA[0], acc1[i][1] + bA[1],
                        acc1[i][2] + bA[2], acc1[i][3] + bA[3]);
        *(float4*)(C1 + (size_t)gr * 128 + tx * 4) = o;
        o = make_float4(acc1[i][4] + bB[0], acc1[i][5] + bB[1],
                        acc1[i][6] + bB[2], acc1[i][7] + bB[3]);
        *(float4*)(C1 + (size_t)gr * 128 + 64 + tx * 4) = o;
      }
    }
  }
}

// ------------------------------------------------------------------
// heads: per comment row r: h = relu(h2[r])
//   tl = h@Wt+bt ; il = h@Wi+bi ; tp=sigmoid(tl) ; ip=softmax(il)
//   ml = [h,tp,ip]@Wm + bm
// one wave per row, butterfly reductions
// ------------------------------------------------------------------
__global__ __launch_bounds__(256) void heads_kernel(
    const float* __restrict__ h2,
    const float* __restrict__ Wt, const float* __restrict__ bt,
    const float* __restrict__ Wi, const float* __restrict__ bi,
    const float* __restrict__ Wm, const float* __restrict__ bm,
    float* __restrict__ out_t, float* __restrict__ out_i,
    float* __restrict__ out_m, int M) {
  const int lane = threadIdx.x & 63;
  const int wave = (blockIdx.x * blockDim.x + threadIdx.x) >> 6;
  const int nw = (gridDim.x * blockDim.x) >> 6;
  const int k0 = lane * 2;

  float wt0[5], wt1[5];
#pragma unroll
  for (int o = 0; o < 5; ++o) { wt0[o] = Wt[k0 * 5 + o]; wt1[o] = Wt[(k0 + 1) * 5 + o]; }
  float wi0[4], wi1[4];
#pragma unroll
  for (int o = 0; o < 4; ++o) { wi0[o] = Wi[k0 * 4 + o]; wi1[o] = Wi[(k0 + 1) * 4 + o]; }
  float wm0[3], wm1[3];
#pragma unroll
  for (int o = 0; o < 3; ++o) { wm0[o] = Wm[k0 * 3 + o]; wm1[o] = Wm[(k0 + 1) * 3 + o]; }
  float btv[5], biv[4], bmv[3];
#pragma unroll
  for (int o = 0; o < 5; ++o) btv[o] = bt[o];
#pragma unroll
  for (int o = 0; o < 4; ++o) biv[o] = bi[o];
#pragma unroll
  for (int o = 0; o < 3; ++o) bmv[o] = bm[o];
  float wmt[5][3], wmi[4][3];
#pragma unroll
  for (int j = 0; j < 5; ++j)
#pragma unroll
    for (int o = 0; o < 3; ++o) wmt[j][o] = Wm[(128 + j) * 3 + o];
#pragma unroll
  for (int j = 0; j < 4; ++j)
#pragma unroll
    for (int o = 0; o < 3; ++o) wmi[j][o] = Wm[(133 + j) * 3 + o];

  for (int row = wave; row < M; row += nw) {
    float2 hv = *(const float2*)(h2 + (size_t)row * 128 + k0);
    float ha = fmaxf(hv.x, 0.f), hb = fmaxf(hv.y, 0.f);
    float tl[5], il[4], mp[3];
#pragma unroll
    for (int o = 0; o < 5; ++o) tl[o] = ha * wt0[o] + hb * wt1[o];
#pragma unroll
    for (int o = 0; o < 4; ++o) il[o] = ha * wi0[o] + hb * wi1[o];
#pragma unroll
    for (int o = 0; o < 3; ++o) mp[o] = ha * wm0[o] + hb * wm1[o];
#pragma unroll
    for (int s = 1; s < 64; s <<= 1) {
#pragma unroll
      for (int o = 0; o < 5; ++o) tl[o] += __shfl_xor(tl[o], s);
#pragma unroll
      for (int o = 0; o < 4; ++o) il[o] += __shfl_xor(il[o], s);
#pragma unroll
      for (int o = 0; o < 3; ++o) mp[o] += __shfl_xor(mp[o], s);
    }
    float t_[5], tp[5];
#pragma unroll
    for (int o = 0; o < 5; ++o) {
      t_[o] = tl[o] + btv[o];
      tp[o] = 1.f / (1.f + __expf(-t_[o]));
    }
    float i_[4];
#pragma unroll
    for (int o = 0; o < 4; ++o) i_[o] = il[o] + biv[o];
    float mx = fmaxf(fmaxf(i_[0], i_[1]), fmaxf(i_[2], i_[3]));
    float ex[4], es = 0.f;
#pragma unroll
    for (int o = 0; o < 4; ++o) { ex[o] = __expf(i_[o] - mx); es += ex[o]; }
    float inv_es = 1.f / es;
    float ml[3];
#pragma unroll
    for (int o = 0; o < 3; ++o) {
      float v = mp[o] + bmv[o];
#pragma unroll
      for (int j = 0; j < 5; ++j) v += tp[j] * wmt[j][o];
#pragma unroll
      for (int j = 0; j < 4; ++j) v += (ex[j] * inv_es) * wmi[j][o];
      ml[o] = v;
    }
    if (lane < 5) out_t[(size_t)row * 5 + lane] = t_[lane];
    else if (lane < 9) out_i[(size_t)row * 4 + (lane - 5)] = i_[lane - 5];
    else if (lane < 12) out_m[(size_t)row * 3 + (lane - 9)] = ml[lane - 9];
  }
}

// ------------------------------------------------------------------
extern "C" void kernel_launch(void* const* d_in, const int* in_sizes, int n_in,
                              void* d_out, int out_size, void* d_ws, size_t ws_size,
                              hipStream_t stream) {
  const float* x_comment = (const float*)d_in[0];
  const float* x_topic   = (const float*)d_in[1];
  const float* x_claim   = (const float*)d_in[2];
  const float* c1s_Wl = (const float*)d_in[3];
  const float* c1s_bl = (const float*)d_in[4];
  const float* c1s_Wr = (const float*)d_in[5];
  const float* c1a_Wl = (const float*)d_in[6];
  const float* c1a_bl = (const float*)d_in[7];
  const float* c1a_Wr = (const float*)d_in[8];
  const float* c1t_Wl = (const float*)d_in[9];
  const float* c1t_bl = (const float*)d_in[10];
  const float* c1t_Wr = (const float*)d_in[11];
  const float* c2s_Wl = (const float*)d_in[12];
  const float* c2s_bl = (const float*)d_in[13];
  const float* c2s_Wr = (const float*)d_in[14];
  const float* c2a_Wl = (const float*)d_in[15];
  const float* c2a_bl = (const float*)d_in[16];
  const float* c2a_Wr = (const float*)d_in[17];
  const float* c2t_Wl = (const float*)d_in[18];
  const float* c2t_bl = (const float*)d_in[19];
  const float* c2t_Wr = (const float*)d_in[20];
  const float* Wt = (const float*)d_in[21];
  const float* bt = (const float*)d_in[22];
  const float* Wi = (const float*)d_in[23];
  const float* bi = (const float*)d_in[24];
  const float* Wm = (const float*)d_in[25];
  const float* bm = (const float*)d_in[26];
  const int* ei_sim = (const int*)d_in[27];
  const int* ei_ab  = (const int*)d_in[28];
  const int* ei_tg  = (const int*)d_in[29];

  const int E_sim = in_sizes[27] / 2;
  const int E_ab  = in_sizes[28] / 2;
  const int E_tg  = in_sizes[29] / 2;
  const int N_T = in_sizes[1] / 128;   // 5000
  const int N_CL = in_sizes[2] / 128;  // 20000

  float* ws = (float*)d_ws;
  // workspace layout (float offsets)
  float* y_s  = ws;                       // N_C*128 = 12.8M
  float* h1   = ws + 12800000;            // 12.8M
  float* h2   = ws + 25600000;            // 12.8M
  float* y_a  = ws + 38400000;            // 640K
  float* y_t  = ws + 39040000;            // 2.56M
  int*   cnt  = (int*)(ws + 41600000);    // 3*N_C ints
  float* inv  = ws + 41900000;            // 3*N_C floats
  float* W1s  = ws + 42200000;            // 256*128
  float* b1s  = ws + 42232768;            // 128
  float* W2s  = ws + 42232896;            // 128*128
  float* b2s  = ws + 42249280;            // 128

  // degree counts + inverse
  hipMemsetAsync(cnt, 0, 3 * N_C * sizeof(int), stream);
  count_kernel<<<(E_sim + 255) / 256, 256, 0, stream>>>(ei_sim, cnt, E_sim);
  count_kernel<<<(E_ab + 255) / 256, 256, 0, stream>>>(ei_ab, cnt + N_C, E_ab);
  count_kernel<<<(E_tg + 255) / 256, 256, 0, stream>>>(ei_tg, cnt + 2 * N_C, E_tg);
  inv_kernel<<<(3 * N_C + 255) / 256, 256, 0, stream>>>(cnt, inv, 3 * N_C);

  // folded Wr / bias sums
  add3_kernel<<<(256 * 128 + 255) / 256, 256, 0, stream>>>(c1s_Wr, c1a_Wr, c1t_Wr, W1s, 256 * 128);
  add3_kernel<<<1, 256, 0, stream>>>(c1s_bl, c1a_bl, c1t_bl, b1s, 128);
  add3_kernel<<<(128 * 128 + 255) / 256, 256, 0, stream>>>(c2s_Wr, c2a_Wr, c2t_Wr, W2s, 128 * 128);
  add3_kernel<<<1, 256, 0, stream>>>(c2s_bl, c2a_bl, c2t_bl, b2s, 128);

  // ---------------- layer 1 ----------------
  // y_s = x_comment@c1s_Wl ; h1 = x_comment@W1s + b1s
  gemm_kernel<true, false><<<(N_C + 63) / 64, 256, 0, stream>>>(
      x_comment, 256, N_C, c1s_Wl, W1s, y_s, h1, b1s);
  gemm_kernel<false, false><<<(N_T + 63) / 64, 256, 0, stream>>>(
      x_topic, 128, N_T, c1a_Wl, nullptr, y_a, nullptr, nullptr);
  gemm_kernel<false, false><<<(N_CL + 63) / 64, 256, 0, stream>>>(
      x_claim, 128, N_CL, c1t_Wl, nullptr, y_t, nullptr, nullptr);

  scatter_kernel<<<(E_sim + 7) / 8, 256, 0, stream>>>(y_s, ei_sim, inv, h1, E_sim);
  scatter_kernel<<<(E_ab + 7) / 8, 256, 0, stream>>>(y_a, ei_ab, inv + N_C, h1, E_ab);
  scatter_kernel<<<(E_tg + 7) / 8, 256, 0, stream>>>(y_t, ei_tg, inv + 2 * N_C, h1, E_tg);

  // ---------------- layer 2 ----------------
  // y_s = relu(h1)@c2s_Wl ; h2 = relu(h1)@W2s + b2s
  gemm_kernel<true, true><<<(N_C + 63) / 64, 256, 0, stream>>>(
      h1, 128, N_C, c2s_Wl, W2s, y_s, h2, b2s);
  gemm_kernel<false, false><<<(N_T + 63) / 64, 256, 0, stream>>>(
      x_topic, 128, N_T, c2a_Wl, nullptr, y_a, nullptr, nullptr);
  gemm_kernel<false, false><<<(N_CL + 63) / 64, 256, 0, stream>>>(
      x_claim, 128, N_CL, c2t_Wl, nullptr, y_t, nullptr, nullptr);

  scatter_kernel<<<(E_sim + 7) / 8, 256, 0, stream>>>(y_s, ei_sim, inv, h2, E_sim);
  scatter_kernel<<<(E_ab + 7) / 8, 256, 0, stream>>>(y_a, ei_ab, inv + N_C, h2, E_ab);
  scatter_kernel<<<(E_tg + 7) / 8, 256, 0, stream>>>(y_t, ei_tg, inv + 2 * N_C, h2, E_tg);

  // ---------------- heads ----------------
  float* out = (float*)d_out;
  heads_kernel<<<1024, 256, 0, stream>>>(
      h2, Wt, bt, Wi, bi, Wm, bm,
      out, out + (size_t)N_C * 5, out + (size_t)N_C * 9, N_C);
}

// Round 2
// 1037.226 us; speedup vs baseline: 4.5181x; 4.5181x over previous
//
#include <hip/hip_runtime.h>
#include <math.h>

#define N_C 100000
#define HD 128
#define SCAN_CHUNK 1024

// ------------------------------------------------------------------
// prep kernels
// ------------------------------------------------------------------
__global__ void count_kernel(const int* __restrict__ ei, int* __restrict__ cnt, int E) {
  int e = blockIdx.x * 256 + threadIdx.x;
  if (e < E) atomicAdd(&cnt[ei[E + e]], 1);
}

__global__ void inv_kernel(const int* __restrict__ cnt, float* __restrict__ inv, int n) {
  int i = blockIdx.x * 256 + threadIdx.x;
  if (i < n) inv[i] = 1.0f / fmaxf((float)cnt[i], 1.0f);
}

__global__ void add3_kernel(const float* __restrict__ a, const float* __restrict__ b,
                            const float* __restrict__ c, float* __restrict__ o, int n) {
  int i = blockIdx.x * 256 + threadIdx.x;
  if (i < n) o[i] = a[i] + b[i] + c[i];
}

// ------------------------------------------------------------------
// 3-phase exclusive scan (counting-sort offsets), n up to ~128K
// ------------------------------------------------------------------
__global__ __launch_bounds__(256) void scan_phaseA(const int* __restrict__ cnt,
                                                   int* __restrict__ partial, int n) {
  __shared__ int sdata[256];
  int base = blockIdx.x * SCAN_CHUNK + threadIdx.x * 4;
  int s = 0;
#pragma unroll
  for (int j = 0; j < 4; ++j) {
    int idx = base + j;
    if (idx < n) s += cnt[idx];
  }
  sdata[threadIdx.x] = s;
  __syncthreads();
  for (int off = 128; off > 0; off >>= 1) {
    if (threadIdx.x < off) sdata[threadIdx.x] += sdata[threadIdx.x + off];
    __syncthreads();
  }
  if (threadIdx.x == 0) partial[blockIdx.x] = sdata[0];
}

__global__ __launch_bounds__(256) void scan_phaseB(int* __restrict__ partial, int nb) {
  __shared__ int sdata[256];
  int t = threadIdx.x;
  int v = (t < nb) ? partial[t] : 0;
  sdata[t] = v;
  __syncthreads();
  for (int off = 1; off < 256; off <<= 1) {
    int x = (t >= off) ? sdata[t - off] : 0;
    __syncthreads();
    sdata[t] += x;
    __syncthreads();
  }
  if (t < nb) partial[t] = sdata[t] - v;  // exclusive
}

__global__ __launch_bounds__(256) void scan_phaseC(const int* __restrict__ cnt,
                                                   const int* __restrict__ partial,
                                                   int* __restrict__ rs, int n) {
  __shared__ int sdata[256];
  int t = threadIdx.x;
  int base = blockIdx.x * SCAN_CHUNK + t * 4;
  int v[4];
  int s = 0;
#pragma unroll
  for (int j = 0; j < 4; ++j) {
    int idx = base + j;
    v[j] = (idx < n) ? cnt[idx] : 0;
    s += v[j];
  }
  sdata[t] = s;
  __syncthreads();
  for (int off = 1; off < 256; off <<= 1) {
    int x = (t >= off) ? sdata[t - off] : 0;
    __syncthreads();
    sdata[t] += x;
    __syncthreads();
  }
  int run = sdata[t] - s + partial[blockIdx.x];
#pragma unroll
  for (int j = 0; j < 4; ++j) {
    int idx = base + j;
    if (idx < n) rs[idx] = run;
    run += v[j];
  }
}

__global__ void set_totals(int* rs_s, int Es, int* rs_a, int Ea, int* rs_t, int Et, int n) {
  if (threadIdx.x == 0) {
    rs_s[n] = Es;
    rs_a[n] = Ea;
    rs_t[n] = Et;
  }
}

__global__ void place_kernel(const int* __restrict__ ei, const int* __restrict__ rs,
                             int* __restrict__ fill, int* __restrict__ srcs, int E) {
  int e = blockIdx.x * 256 + threadIdx.x;
  if (e < E) {
    int d = ei[E + e];
    int p = rs[d] + atomicAdd(&fill[d], 1);
    srcs[p] = ei[e];
  }
}

// ------------------------------------------------------------------
// fused CSR gather for all 3 edge types: h[row] += sum_type inv_type[row] *
// sum_e y_type[src_e]. One wave per row, float2 per lane (512B/edge read).
// Non-atomic RMW: single writer per row.
// ------------------------------------------------------------------
__global__ __launch_bounds__(256) void gather_kernel(
    const float* __restrict__ ys, const float* __restrict__ ya, const float* __restrict__ yt,
    const int* __restrict__ rs_s, const int* __restrict__ src_s,
    const int* __restrict__ rs_a, const int* __restrict__ src_a,
    const int* __restrict__ rs_t, const int* __restrict__ src_t,
    const float* __restrict__ inv, float* h, int M) {
  int row = blockIdx.x * 4 + (threadIdx.x >> 6);
  if (row >= M) return;
  int lane = threadIdx.x & 63;
  int o = lane * 2;
  float ax = 0.f, ay = 0.f;
  {
    int b = rs_s[row], e = rs_s[row + 1];
    float sx = 0.f, sy = 0.f;
    for (int i = b; i < e; ++i) {
      const float2 v = *(const float2*)(ys + (size_t)src_s[i] * HD + o);
      sx += v.x; sy += v.y;
    }
    float sc = inv[row];
    ax += sx * sc; ay += sy * sc;
  }
  {
    int b = rs_a[row], e = rs_a[row + 1];
    float sx = 0.f, sy = 0.f;
    for (int i = b; i < e; ++i) {
      const float2 v = *(const float2*)(ya + (size_t)src_a[i] * HD + o);
      sx += v.x; sy += v.y;
    }
    float sc = inv[M + row];
    ax += sx * sc; ay += sy * sc;
  }
  {
    int b = rs_t[row], e = rs_t[row + 1];
    float sx = 0.f, sy = 0.f;
    for (int i = b; i < e; ++i) {
      const float2 v = *(const float2*)(yt + (size_t)src_t[i] * HD + o);
      sx += v.x; sy += v.y;
    }
    float sc = inv[2 * M + row];
    ax += sx * sc; ay += sy * sc;
  }
  float2 b0 = *(const float2*)(h + (size_t)row * HD + o);
  b0.x += ax;
  b0.y += ay;
  *(float2*)(h + (size_t)row * HD + o) = b0;
}

// ------------------------------------------------------------------
// fp32 tiled GEMM: C0 = act(A)@B0 [, C1 = act(A)@B1 + bias1]
// NOTE: A and C1 intentionally NOT __restrict__ (L2 call uses C1 == A
// in-place; safe because each block reads only its own 64 A-rows in the
// k-loop and writes them only in the epilogue after the final barrier).
// ------------------------------------------------------------------
template <bool DUAL, bool RELUA>
__global__ __launch_bounds__(256) void gemm_kernel(
    const float* A, int K, int M,
    const float* __restrict__ B0, const float* __restrict__ B1,
    float* __restrict__ C0, float* C1,
    const float* __restrict__ bias1) {
  constexpr int BM = 64, BK = 16;
  __shared__ float As[BK][BM + 4];
  __shared__ float Bs0[BK][128];
  __shared__ float Bs1[DUAL ? BK : 1][DUAL ? 128 : 4];

  const int t = threadIdx.x;
  const int m0 = blockIdx.x * BM;
  const int ty = t >> 4;
  const int tx = t & 15;
  const int arow = t >> 2;
  const int acol = (t & 3) * 4;
  const int brow = t >> 5;
  const int bcol = (t & 31) * 4;

  float acc0[4][8];
  float acc1[DUAL ? 4 : 1][DUAL ? 8 : 1];
#pragma unroll
  for (int i = 0; i < 4; ++i)
#pragma unroll
    for (int j = 0; j < 8; ++j) acc0[i][j] = 0.f;
  if constexpr (DUAL) {
#pragma unroll
    for (int i = 0; i < 4; ++i)
#pragma unroll
      for (int j = 0; j < 8; ++j) acc1[i][j] = 0.f;
  }

  const int gr_a = m0 + arow;
  const bool a_ok = gr_a < M;
  const float* Arow = A + (size_t)gr_a * K;

  for (int k0 = 0; k0 < K; k0 += BK) {
    float4 av = make_float4(0.f, 0.f, 0.f, 0.f);
    if (a_ok) av = *(const float4*)(Arow + k0 + acol);
    if (RELUA) {
      av.x = fmaxf(av.x, 0.f); av.y = fmaxf(av.y, 0.f);
      av.z = fmaxf(av.z, 0.f); av.w = fmaxf(av.w, 0.f);
    }
    As[acol + 0][arow] = av.x;
    As[acol + 1][arow] = av.y;
    As[acol + 2][arow] = av.z;
    As[acol + 3][arow] = av.w;
#pragma unroll
    for (int r = 0; r < BK; r += 8) {
      *(float4*)&Bs0[r + brow][bcol] =
          *(const float4*)(B0 + (size_t)(k0 + r + brow) * 128 + bcol);
      if constexpr (DUAL) {
        *(float4*)&Bs1[r + brow][bcol] =
            *(const float4*)(B1 + (size_t)(k0 + r + brow) * 128 + bcol);
      }
    }
    __syncthreads();
#pragma unroll
    for (int kk = 0; kk < BK; ++kk) {
      float4 af = *(const float4*)&As[kk][ty * 4];
      float a[4] = {af.x, af.y, af.z, af.w};
      float b0[8];
      *(float4*)&b0[0] = *(const float4*)&Bs0[kk][tx * 4];
      *(float4*)&b0[4] = *(const float4*)&Bs0[kk][64 + tx * 4];
#pragma unroll
      for (int i = 0; i < 4; ++i)
#pragma unroll
        for (int j = 0; j < 8; ++j) acc0[i][j] += a[i] * b0[j];
      if constexpr (DUAL) {
        float b1[8];
        *(float4*)&b1[0] = *(const float4*)&Bs1[kk][tx * 4];
        *(float4*)&b1[4] = *(const float4*)&Bs1[kk][64 + tx * 4];
#pragma unroll
        for (int i = 0; i < 4; ++i)
#pragma unroll
          for (int j = 0; j < 8; ++j) acc1[i][j] += a[i] * b1[j];
      }
    }
    __syncthreads();
  }

  float bA[4] = {0.f, 0.f, 0.f, 0.f}, bB[4] = {0.f, 0.f, 0.f, 0.f};
  if constexpr (DUAL) {
#pragma unroll
    for (int j = 0; j < 4; ++j) {
      bA[j] = bias1[tx * 4 + j];
      bB[j] = bias1[64 + tx * 4 + j];
    }
  }
#pragma unroll
  for (int i = 0; i < 4; ++i) {
    int gr = m0 + ty * 4 + i;
    if (gr < M) {
      float4 o;
      o = make_float4(acc0[i][0], acc0[i][1], acc0[i][2], acc0[i][3]);
      *(float4*)(C0 + (size_t)gr * 128 + tx * 4) = o;
      o = make_float4(acc0[i][4], acc0[i][5], acc0[i][6], acc0[i][7]);
      *(float4*)(C0 + (size_t)gr * 128 + 64 + tx * 4) = o;
      if constexpr (DUAL) {
        o = make_float4(acc1[i][0] + bA[0], acc1[i][1] + bA[1],
                        acc1[i][2] + bA[2], acc1[i][3] + bA[3]);
        *(float4*)(C1 + (size_t)gr * 128 + tx * 4) = o;
        o = make_float4(acc1[i][4] + bB[0], acc1[i][5] + bB[1],
                        acc1[i][6] + bB[2], acc1[i][7] + bB[3]);
        *(float4*)(C1 + (size_t)gr * 128 + 64 + tx * 4) = o;
      }
    }
  }
}

// ------------------------------------------------------------------
// heads
// ------------------------------------------------------------------
__global__ __launch_bounds__(256) void heads_kernel(
    const float* __restrict__ h2,
    const float* __restrict__ Wt, const float* __restrict__ bt,
    const float* __restrict__ Wi, const float* __restrict__ bi,
    const float* __restrict__ Wm, const float* __restrict__ bm,
    float* __restrict__ out_t, float* __restrict__ out_i,
    float* __restrict__ out_m, int M) {
  const int lane = threadIdx.x & 63;
  const int wave = (blockIdx.x * blockDim.x + threadIdx.x) >> 6;
  const int nw = (gridDim.x * blockDim.x) >> 6;
  const int k0 = lane * 2;

  float wt0[5], wt1[5];
#pragma unroll
  for (int o = 0; o < 5; ++o) { wt0[o] = Wt[k0 * 5 + o]; wt1[o] = Wt[(k0 + 1) * 5 + o]; }
  float wi0[4], wi1[4];
#pragma unroll
  for (int o = 0; o < 4; ++o) { wi0[o] = Wi[k0 * 4 + o]; wi1[o] = Wi[(k0 + 1) * 4 + o]; }
  float wm0[3], wm1[3];
#pragma unroll
  for (int o = 0; o < 3; ++o) { wm0[o] = Wm[k0 * 3 + o]; wm1[o] = Wm[(k0 + 1) * 3 + o]; }
  float btv[5], biv[4], bmv[3];
#pragma unroll
  for (int o = 0; o < 5; ++o) btv[o] = bt[o];
#pragma unroll
  for (int o = 0; o < 4; ++o) biv[o] = bi[o];
#pragma unroll
  for (int o = 0; o < 3; ++o) bmv[o] = bm[o];
  float wmt[5][3], wmi[4][3];
#pragma unroll
  for (int j = 0; j < 5; ++j)
#pragma unroll
    for (int o = 0; o < 3; ++o) wmt[j][o] = Wm[(128 + j) * 3 + o];
#pragma unroll
  for (int j = 0; j < 4; ++j)
#pragma unroll
    for (int o = 0; o < 3; ++o) wmi[j][o] = Wm[(133 + j) * 3 + o];

  for (int row = wave; row < M; row += nw) {
    float2 hv = *(const float2*)(h2 + (size_t)row * 128 + k0);
    float ha = fmaxf(hv.x, 0.f), hb = fmaxf(hv.y, 0.f);
    float tl[5], il[4], mp[3];
#pragma unroll
    for (int o = 0; o < 5; ++o) tl[o] = ha * wt0[o] + hb * wt1[o];
#pragma unroll
    for (int o = 0; o < 4; ++o) il[o] = ha * wi0[o] + hb * wi1[o];
#pragma unroll
    for (int o = 0; o < 3; ++o) mp[o] = ha * wm0[o] + hb * wm1[o];
#pragma unroll
    for (int s = 1; s < 64; s <<= 1) {
#pragma unroll
      for (int o = 0; o < 5; ++o) tl[o] += __shfl_xor(tl[o], s);
#pragma unroll
      for (int o = 0; o < 4; ++o) il[o] += __shfl_xor(il[o], s);
#pragma unroll
      for (int o = 0; o < 3; ++o) mp[o] += __shfl_xor(mp[o], s);
    }
    float t_[5], tp[5];
#pragma unroll
    for (int o = 0; o < 5; ++o) {
      t_[o] = tl[o] + btv[o];
      tp[o] = 1.f / (1.f + __expf(-t_[o]));
    }
    float i_[4];
#pragma unroll
    for (int o = 0; o < 4; ++o) i_[o] = il[o] + biv[o];
    float mx = fmaxf(fmaxf(i_[0], i_[1]), fmaxf(i_[2], i_[3]));
    float ex[4], es = 0.f;
#pragma unroll
    for (int o = 0; o < 4; ++o) { ex[o] = __expf(i_[o] - mx); es += ex[o]; }
    float inv_es = 1.f / es;
    float ml[3];
#pragma unroll
    for (int o = 0; o < 3; ++o) {
      float v = mp[o] + bmv[o];
#pragma unroll
      for (int j = 0; j < 5; ++j) v += tp[j] * wmt[j][o];
#pragma unroll
      for (int j = 0; j < 4; ++j) v += (ex[j] * inv_es) * wmi[j][o];
      ml[o] = v;
    }
    if (lane < 5) out_t[(size_t)row * 5 + lane] = t_[lane];
    else if (lane < 9) out_i[(size_t)row * 4 + (lane - 5)] = i_[lane - 5];
    else if (lane < 12) out_m[(size_t)row * 3 + (lane - 9)] = ml[lane - 9];
  }
}

// ------------------------------------------------------------------
extern "C" void kernel_launch(void* const* d_in, const int* in_sizes, int n_in,
                              void* d_out, int out_size, void* d_ws, size_t ws_size,
                              hipStream_t stream) {
  const float* x_comment = (const float*)d_in[0];
  const float* x_topic   = (const float*)d_in[1];
  const float* x_claim   = (const float*)d_in[2];
  const float* c1s_Wl = (const float*)d_in[3];
  const float* c1s_bl = (const float*)d_in[4];
  const float* c1s_Wr = (const float*)d_in[5];
  const float* c1a_Wl = (const float*)d_in[6];
  const float* c1a_bl = (const float*)d_in[7];
  const float* c1a_Wr = (const float*)d_in[8];
  const float* c1t_Wl = (const float*)d_in[9];
  const float* c1t_bl = (const float*)d_in[10];
  const float* c1t_Wr = (const float*)d_in[11];
  const float* c2s_Wl = (const float*)d_in[12];
  const float* c2s_bl = (const float*)d_in[13];
  const float* c2s_Wr = (const float*)d_in[14];
  const float* c2a_Wl = (const float*)d_in[15];
  const float* c2a_bl = (const float*)d_in[16];
  const float* c2a_Wr = (const float*)d_in[17];
  const float* c2t_Wl = (const float*)d_in[18];
  const float* c2t_bl = (const float*)d_in[19];
  const float* c2t_Wr = (const float*)d_in[20];
  const float* Wt = (const float*)d_in[21];
  const float* bt = (const float*)d_in[22];
  const float* Wi = (const float*)d_in[23];
  const float* bi = (const float*)d_in[24];
  const float* Wm = (const float*)d_in[25];
  const float* bm = (const float*)d_in[26];
  const int* ei_sim = (const int*)d_in[27];
  const int* ei_ab  = (const int*)d_in[28];
  const int* ei_tg  = (const int*)d_in[29];

  const int E_sim = in_sizes[27] / 2;
  const int E_ab  = in_sizes[28] / 2;
  const int E_tg  = in_sizes[29] / 2;
  const int N_T = in_sizes[1] / 128;
  const int N_CL = in_sizes[2] / 128;

  float* ws = (float*)d_ws;
  // workspace layout (element offsets; total ~31.1M elems = 125 MB)
  float* y_s   = ws;                        // 12.8M
  float* h1    = ws + 12800000;             // 12.8M (layer2 output in-place)
  float* y_a   = ws + 25600000;             // 640K
  float* y_t   = ws + 26240000;             // 2.56M
  int*   cnt   = (int*)(ws + 28800000);     // 3*N_C (reused as fill)
  float* inv   = ws + 29100000;             // 3*N_C
  int*   rs_s  = (int*)(ws + 29400000);     // N_C+1
  int*   rs_a  = (int*)(ws + 29510000);     // N_C+1
  int*   rs_t  = (int*)(ws + 29620000);     // N_C+1
  int*   src_s = (int*)(ws + 29730000);     // E_sim
  int*   src_a = (int*)(ws + 30330000);     // E_ab
  int*   src_t = (int*)(ws + 30630000);     // E_tg
  int*   part  = (int*)(ws + 30930000);     // 3*128 scan partials
  float* W1s   = ws + 30940000;             // 256*128
  float* b1s   = ws + 30980000;             // 128
  float* W2s   = ws + 30990000;             // 128*128
  float* b2s   = ws + 31010000;             // 128

  const int nbS = (N_C + SCAN_CHUNK - 1) / SCAN_CHUNK;  // 98

  // ---- degree histogram + inverse ----
  hipMemsetAsync(cnt, 0, 3 * N_C * sizeof(int), stream);
  count_kernel<<<(E_sim + 255) / 256, 256, 0, stream>>>(ei_sim, cnt, E_sim);
  count_kernel<<<(E_ab + 255) / 256, 256, 0, stream>>>(ei_ab, cnt + N_C, E_ab);
  count_kernel<<<(E_tg + 255) / 256, 256, 0, stream>>>(ei_tg, cnt + 2 * N_C, E_tg);
  inv_kernel<<<(3 * N_C + 255) / 256, 256, 0, stream>>>(cnt, inv, 3 * N_C);

  // ---- CSR build (counting sort) ----
  scan_phaseA<<<nbS, 256, 0, stream>>>(cnt, part, N_C);
  scan_phaseB<<<1, 256, 0, stream>>>(part, nbS);
  scan_phaseC<<<nbS, 256, 0, stream>>>(cnt, part, rs_s, N_C);
  scan_phaseA<<<nbS, 256, 0, stream>>>(cnt + N_C, part + 128, N_C);
  scan_phaseB<<<1, 256, 0, stream>>>(part + 128, nbS);
  scan_phaseC<<<nbS, 256, 0, stream>>>(cnt + N_C, part + 128, rs_a, N_C);
  scan_phaseA<<<nbS, 256, 0, stream>>>(cnt + 2 * N_C, part + 256, N_C);
  scan_phaseB<<<1, 256, 0, stream>>>(part + 256, nbS);
  scan_phaseC<<<nbS, 256, 0, stream>>>(cnt + 2 * N_C, part + 256, rs_t, N_C);
  set_totals<<<1, 64, 0, stream>>>(rs_s, E_sim, rs_a, E_ab, rs_t, E_tg, N_C);

  hipMemsetAsync(cnt, 0, 3 * N_C * sizeof(int), stream);  // reuse as fill
  place_kernel<<<(E_sim + 255) / 256, 256, 0, stream>>>(ei_sim, rs_s, cnt, src_s, E_sim);
  place_kernel<<<(E_ab + 255) / 256, 256, 0, stream>>>(ei_ab, rs_a, cnt + N_C, src_a, E_ab);
  place_kernel<<<(E_tg + 255) / 256, 256, 0, stream>>>(ei_tg, rs_t, cnt + 2 * N_C, src_t, E_tg);

  // ---- folded Wr / bias sums ----
  add3_kernel<<<(256 * 128 + 255) / 256, 256, 0, stream>>>(c1s_Wr, c1a_Wr, c1t_Wr, W1s, 256 * 128);
  add3_kernel<<<1, 256, 0, stream>>>(c1s_bl, c1a_bl, c1t_bl, b1s, 128);
  add3_kernel<<<(128 * 128 + 255) / 256, 256, 0, stream>>>(c2s_Wr, c2a_Wr, c2t_Wr, W2s, 128 * 128);
  add3_kernel<<<1, 256, 0, stream>>>(c2s_bl, c2a_bl, c2t_bl, b2s, 128);

  // ---------------- layer 1 ----------------
  gemm_kernel<true, false><<<(N_C + 63) / 64, 256, 0, stream>>>(
      x_comment, 256, N_C, c1s_Wl, W1s, y_s, h1, b1s);
  gemm_kernel<false, false><<<(N_T + 63) / 64, 256, 0, stream>>>(
      x_topic, 128, N_T, c1a_Wl, nullptr, y_a, nullptr, nullptr);
  gemm_kernel<false, false><<<(N_CL + 63) / 64, 256, 0, stream>>>(
      x_claim, 128, N_CL, c1t_Wl, nullptr, y_t, nullptr, nullptr);

  gather_kernel<<<(N_C + 3) / 4, 256, 0, stream>>>(
      y_s, y_a, y_t, rs_s, src_s, rs_a, src_a, rs_t, src_t, inv, h1, N_C);

  // ---------------- layer 2 (h2 in-place over h1) ----------------
  gemm_kernel<true, true><<<(N_C + 63) / 64, 256, 0, stream>>>(
      h1, 128, N_C, c2s_Wl, W2s, y_s, h1, b2s);
  gemm_kernel<false, false><<<(N_T + 63) / 64, 256, 0, stream>>>(
      x_topic, 128, N_T, c2a_Wl, nullptr, y_a, nullptr, nullptr);
  gemm_kernel<false, false><<<(N_CL + 63) / 64, 256, 0, stream>>>(
      x_claim, 128, N_CL, c2t_Wl, nullptr, y_t, nullptr, nullptr);

  gather_kernel<<<(N_C + 3) / 4, 256, 0, stream>>>(
      y_s, y_a, y_t, rs_s, src_s, rs_a, src_a, rs_t, src_t, inv, h1, N_C);

  // ---------------- heads ----------------
  float* out = (float*)d_out;
  heads_kernel<<<1024, 256, 0, stream>>>(
      h1, Wt, bt, Wi, bi, Wm, bm,
      out, out + (size_t)N_C * 5, out + (size_t)N_C * 9, N_C);
}

// Round 3
// 853.837 us; speedup vs baseline: 5.4885x; 1.2148x over previous
//
#include <hip/hip_runtime.h>
#include <math.h>

#define N_C 100000
#define HD 128
#define SCAN_CHUNK 1024

typedef short v8s __attribute__((ext_vector_type(8)));
typedef float v4f __attribute__((ext_vector_type(4)));

__device__ __forceinline__ unsigned short f2bf(float f) {
  unsigned int u = __float_as_uint(f);
  u += 0x7fffu + ((u >> 16) & 1u);
  return (unsigned short)(u >> 16);
}

// ------------------------------------------------------------------
// prep kernels
// ------------------------------------------------------------------
__global__ void count_kernel(const int* __restrict__ ei, int* __restrict__ cnt, int E) {
  int e = blockIdx.x * 256 + threadIdx.x;
  if (e < E) atomicAdd(&cnt[ei[E + e]], 1);
}

__global__ void inv_kernel(const int* __restrict__ cnt, float* __restrict__ inv, int n) {
  int i = blockIdx.x * 256 + threadIdx.x;
  if (i < n) inv[i] = 1.0f / fmaxf((float)cnt[i], 1.0f);
}

__global__ void add3_kernel(const float* __restrict__ a, const float* __restrict__ b,
                            const float* __restrict__ c, float* __restrict__ o, int n) {
  int i = blockIdx.x * 256 + threadIdx.x;
  if (i < n) o[i] = a[i] + b[i] + c[i];
}

// transpose + cvt: in [K x 128] fp32 -> out [128 x K] bf16
__global__ void tcvt_kernel(const float* __restrict__ in, unsigned short* __restrict__ out, int K) {
  int idx = blockIdx.x * 256 + threadIdx.x;
  if (idx < K * 128) {
    int k = idx >> 7, n = idx & 127;
    out[n * K + k] = f2bf(in[idx]);
  }
}

__global__ void tcvt3_kernel(const float* __restrict__ a, const float* __restrict__ b,
                             const float* __restrict__ c, unsigned short* __restrict__ out, int K) {
  int idx = blockIdx.x * 256 + threadIdx.x;
  if (idx < K * 128) {
    int k = idx >> 7, n = idx & 127;
    out[n * K + k] = f2bf(a[idx] + b[idx] + c[idx]);
  }
}

// ------------------------------------------------------------------
// 3-phase exclusive scan
// ------------------------------------------------------------------
__global__ __launch_bounds__(256) void scan_phaseA(const int* __restrict__ cnt,
                                                   int* __restrict__ partial, int n) {
  __shared__ int sdata[256];
  int base = blockIdx.x * SCAN_CHUNK + threadIdx.x * 4;
  int s = 0;
#pragma unroll
  for (int j = 0; j < 4; ++j) {
    int idx = base + j;
    if (idx < n) s += cnt[idx];
  }
  sdata[threadIdx.x] = s;
  __syncthreads();
  for (int off = 128; off > 0; off >>= 1) {
    if (threadIdx.x < off) sdata[threadIdx.x] += sdata[threadIdx.x + off];
    __syncthreads();
  }
  if (threadIdx.x == 0) partial[blockIdx.x] = sdata[0];
}

__global__ __launch_bounds__(256) void scan_phaseB(int* __restrict__ partial, int nb) {
  __shared__ int sdata[256];
  int t = threadIdx.x;
  int v = (t < nb) ? partial[t] : 0;
  sdata[t] = v;
  __syncthreads();
  for (int off = 1; off < 256; off <<= 1) {
    int x = (t >= off) ? sdata[t - off] : 0;
    __syncthreads();
    sdata[t] += x;
    __syncthreads();
  }
  if (t < nb) partial[t] = sdata[t] - v;
}

__global__ __launch_bounds__(256) void scan_phaseC(const int* __restrict__ cnt,
                                                   const int* __restrict__ partial,
                                                   int* __restrict__ rs, int n) {
  __shared__ int sdata[256];
  int t = threadIdx.x;
  int base = blockIdx.x * SCAN_CHUNK + t * 4;
  int v[4];
  int s = 0;
#pragma unroll
  for (int j = 0; j < 4; ++j) {
    int idx = base + j;
    v[j] = (idx < n) ? cnt[idx] : 0;
    s += v[j];
  }
  sdata[t] = s;
  __syncthreads();
  for (int off = 1; off < 256; off <<= 1) {
    int x = (t >= off) ? sdata[t - off] : 0;
    __syncthreads();
    sdata[t] += x;
    __syncthreads();
  }
  int run = sdata[t] - s + partial[blockIdx.x];
#pragma unroll
  for (int j = 0; j < 4; ++j) {
    int idx = base + j;
    if (idx < n) rs[idx] = run;
    run += v[j];
  }
}

__global__ void set_totals(int* rs_s, int Es, int* rs_a, int Ea, int* rs_t, int Et, int n) {
  if (threadIdx.x == 0) {
    rs_s[n] = Es;
    rs_a[n] = Ea;
    rs_t[n] = Et;
  }
}

__global__ void place_kernel(const int* __restrict__ ei, const int* __restrict__ rs,
                             int* __restrict__ fill, int* __restrict__ srcs, int E) {
  int e = blockIdx.x * 256 + threadIdx.x;
  if (e < E) {
    int d = ei[E + e];
    int p = rs[d] + atomicAdd(&fill[d], 1);
    srcs[p] = ei[e];
  }
}

// ------------------------------------------------------------------
// MFMA GEMM: C0(bf16) = act(A)@B0 [, C1(fp32) = act(A)@B1 + bias1]
// A: M x KD fp32 row-major (cvt to bf16 in LDS staging)
// B0t/B1t: 128 x KD bf16, n-major (pre-transposed)
// tile 128x128, 4 waves 2x2, BK=64, mfma 16x16x32 bf16
// NOTE: A/C1 not __restrict__ — layer-2 call runs in-place (C1 == A);
// safe: each block reads only its own 128 A-rows, written only in epilogue.
// ------------------------------------------------------------------
template <int KD, bool DUAL, bool RELUA>
__global__ __launch_bounds__(256, 2) void mfma_gemm(
    const float* A, int M,
    const unsigned short* __restrict__ B0t, const unsigned short* __restrict__ B1t,
    unsigned short* __restrict__ C0, float* C1, const float* __restrict__ bias1) {
  constexpr int AST = 72;  // row stride (bf16 elems), 16B-aligned, low conflict
  __shared__ unsigned short As[128 * AST];
  __shared__ unsigned short Bs0[128 * AST];
  __shared__ unsigned short Bs1[DUAL ? 128 * AST : 8];

  const int t = threadIdx.x;
  const int wave = t >> 6, lane = t & 63;
  const int wm = (wave & 1) * 64;   // wave row base
  const int wn = (wave >> 1) * 64;  // wave col base
  const int m0 = blockIdx.x * 128;
  const int lrow = lane & 15, lq = lane >> 4;

  v4f acc0[4][4];
  v4f acc1[DUAL ? 4 : 1][DUAL ? 4 : 1];
#pragma unroll
  for (int i = 0; i < 4; ++i)
#pragma unroll
    for (int j = 0; j < 4; ++j) acc0[i][j] = (v4f)(0.f);
  if constexpr (DUAL) {
#pragma unroll
    for (int i = 0; i < 4; ++i)
#pragma unroll
      for (int j = 0; j < 4; ++j) acc1[i][j] = (v4f)(0.f);
  }

  for (int k0 = 0; k0 < KD; k0 += 64) {
    // ---- stage A tile (128 x 64 fp32 -> bf16), coalesced ----
#pragma unroll
    for (int j = 0; j < 8; ++j) {
      int idx = j * 256 + t;          // 0..2047 float4 slots
      int row = idx >> 4;             // 0..127
      int c4 = idx & 15;              // float4 within 64 cols
      int gr = m0 + row;
      float4 v = make_float4(0.f, 0.f, 0.f, 0.f);
      if (gr < M) v = *(const float4*)(A + (size_t)gr * KD + k0 + c4 * 4);
      if (RELUA) {
        v.x = fmaxf(v.x, 0.f); v.y = fmaxf(v.y, 0.f);
        v.z = fmaxf(v.z, 0.f); v.w = fmaxf(v.w, 0.f);
      }
      unsigned short* d = &As[row * AST + c4 * 4];
      d[0] = f2bf(v.x); d[1] = f2bf(v.y); d[2] = f2bf(v.z); d[3] = f2bf(v.w);
    }
    // ---- stage B tiles (128 x 64 bf16), coalesced 16B copies ----
#pragma unroll
    for (int j = 0; j < 4; ++j) {
      int idx = j * 256 + t;          // 0..1023 16B slots
      int row = idx >> 3;
      int k8 = idx & 7;
      uint4 v = *(const uint4*)(B0t + (size_t)row * KD + k0 + k8 * 8);
      *(uint4*)&Bs0[row * AST + k8 * 8] = v;
      if constexpr (DUAL) {
        uint4 w = *(const uint4*)(B1t + (size_t)row * KD + k0 + k8 * 8);
        *(uint4*)&Bs1[row * AST + k8 * 8] = w;
      }
    }
    __syncthreads();

#pragma unroll
    for (int ks = 0; ks < 2; ++ks) {
      v8s af[4];
#pragma unroll
      for (int mt = 0; mt < 4; ++mt)
        af[mt] = *(const v8s*)&As[(wm + mt * 16 + lrow) * AST + ks * 32 + lq * 8];
#pragma unroll
      for (int cb = 0; cb < 4; ++cb) {
        v8s b0 = *(const v8s*)&Bs0[(wn + cb * 16 + lrow) * AST + ks * 32 + lq * 8];
#pragma unroll
        for (int mt = 0; mt < 4; ++mt)
          acc0[mt][cb] = __builtin_amdgcn_mfma_f32_16x16x32_bf16(af[mt], b0, acc0[mt][cb], 0, 0, 0);
        if constexpr (DUAL) {
          v8s b1 = *(const v8s*)&Bs1[(wn + cb * 16 + lrow) * AST + ks * 32 + lq * 8];
#pragma unroll
          for (int mt = 0; mt < 4; ++mt)
            acc1[mt][cb] = __builtin_amdgcn_mfma_f32_16x16x32_bf16(af[mt], b1, acc1[mt][cb], 0, 0, 0);
        }
      }
    }
    __syncthreads();
  }

  // ---- epilogue: C/D layout col=lane&15, row=lq*4+r ----
  float bv[4] = {0.f, 0.f, 0.f, 0.f};
  if constexpr (DUAL) {
#pragma unroll
    for (int cb = 0; cb < 4; ++cb) bv[cb] = bias1[wn + cb * 16 + lrow];
  }
#pragma unroll
  for (int mt = 0; mt < 4; ++mt) {
#pragma unroll
    for (int r = 0; r < 4; ++r) {
      int gr = m0 + wm + mt * 16 + lq * 4 + r;
      if (gr < M) {
#pragma unroll
        for (int cb = 0; cb < 4; ++cb) {
          int gc = wn + cb * 16 + lrow;
          C0[(size_t)gr * 128 + gc] = f2bf(acc0[mt][cb][r]);
          if constexpr (DUAL) C1[(size_t)gr * 128 + gc] = acc1[mt][cb][r] + bv[cb];
        }
      }
    }
  }
}

// ------------------------------------------------------------------
// fused CSR gather, bf16 sources: h[row] += sum_type inv*sum_e y[src]
// one wave per row, 2 bf16 cols per lane (256B/edge coalesced read)
// ------------------------------------------------------------------
__global__ __launch_bounds__(256) void gather_kernel(
    const unsigned short* __restrict__ ys, const unsigned short* __restrict__ ya,
    const unsigned short* __restrict__ yt,
    const int* __restrict__ rs_s, const int* __restrict__ src_s,
    const int* __restrict__ rs_a, const int* __restrict__ src_a,
    const int* __restrict__ rs_t, const int* __restrict__ src_t,
    const float* __restrict__ inv, float* h, int M) {
  int row = blockIdx.x * 4 + (threadIdx.x >> 6);
  if (row >= M) return;
  int lane = threadIdx.x & 63;
  int o = lane * 2;
  float ax = 0.f, ay = 0.f;
  {
    int b = rs_s[row], e = rs_s[row + 1];
    float sx = 0.f, sy = 0.f;
    for (int i = b; i < e; ++i) {
      unsigned int v = *(const unsigned int*)(ys + (size_t)src_s[i] * HD + o);
      sx += __uint_as_float(v << 16);
      sy += __uint_as_float(v & 0xffff0000u);
    }
    float sc = inv[row];
    ax += sx * sc; ay += sy * sc;
  }
  {
    int b = rs_a[row], e = rs_a[row + 1];
    float sx = 0.f, sy = 0.f;
    for (int i = b; i < e; ++i) {
      unsigned int v = *(const unsigned int*)(ya + (size_t)src_a[i] * HD + o);
      sx += __uint_as_float(v << 16);
      sy += __uint_as_float(v & 0xffff0000u);
    }
    float sc = inv[M + row];
    ax += sx * sc; ay += sy * sc;
  }
  {
    int b = rs_t[row], e = rs_t[row + 1];
    float sx = 0.f, sy = 0.f;
    for (int i = b; i < e; ++i) {
      unsigned int v = *(const unsigned int*)(yt + (size_t)src_t[i] * HD + o);
      sx += __uint_as_float(v << 16);
      sy += __uint_as_float(v & 0xffff0000u);
    }
    float sc = inv[2 * M + row];
    ax += sx * sc; ay += sy * sc;
  }
  float2 b0 = *(const float2*)(h + (size_t)row * HD + o);
  b0.x += ax;
  b0.y += ay;
  *(float2*)(h + (size_t)row * HD + o) = b0;
}

// ------------------------------------------------------------------
// heads
// ------------------------------------------------------------------
__global__ __launch_bounds__(256) void heads_kernel(
    const float* __restrict__ h2,
    const float* __restrict__ Wt, const float* __restrict__ bt,
    const float* __restrict__ Wi, const float* __restrict__ bi,
    const float* __restrict__ Wm, const float* __restrict__ bm,
    float* __restrict__ out_t, float* __restrict__ out_i,
    float* __restrict__ out_m, int M) {
  const int lane = threadIdx.x & 63;
  const int wave = (blockIdx.x * blockDim.x + threadIdx.x) >> 6;
  const int nw = (gridDim.x * blockDim.x) >> 6;
  const int k0 = lane * 2;

  float wt0[5], wt1[5];
#pragma unroll
  for (int o = 0; o < 5; ++o) { wt0[o] = Wt[k0 * 5 + o]; wt1[o] = Wt[(k0 + 1) * 5 + o]; }
  float wi0[4], wi1[4];
#pragma unroll
  for (int o = 0; o < 4; ++o) { wi0[o] = Wi[k0 * 4 + o]; wi1[o] = Wi[(k0 + 1) * 4 + o]; }
  float wm0[3], wm1[3];
#pragma unroll
  for (int o = 0; o < 3; ++o) { wm0[o] = Wm[k0 * 3 + o]; wm1[o] = Wm[(k0 + 1) * 3 + o]; }
  float btv[5], biv[4], bmv[3];
#pragma unroll
  for (int o = 0; o < 5; ++o) btv[o] = bt[o];
#pragma unroll
  for (int o = 0; o < 4; ++o) biv[o] = bi[o];
#pragma unroll
  for (int o = 0; o < 3; ++o) bmv[o] = bm[o];
  float wmt[5][3], wmi[4][3];
#pragma unroll
  for (int j = 0; j < 5; ++j)
#pragma unroll
    for (int o = 0; o < 3; ++o) wmt[j][o] = Wm[(128 + j) * 3 + o];
#pragma unroll
  for (int j = 0; j < 4; ++j)
#pragma unroll
    for (int o = 0; o < 3; ++o) wmi[j][o] = Wm[(133 + j) * 3 + o];

  for (int row = wave; row < M; row += nw) {
    float2 hv = *(const float2*)(h2 + (size_t)row * 128 + k0);
    float ha = fmaxf(hv.x, 0.f), hb = fmaxf(hv.y, 0.f);
    float tl[5], il[4], mp[3];
#pragma unroll
    for (int o = 0; o < 5; ++o) tl[o] = ha * wt0[o] + hb * wt1[o];
#pragma unroll
    for (int o = 0; o < 4; ++o) il[o] = ha * wi0[o] + hb * wi1[o];
#pragma unroll
    for (int o = 0; o < 3; ++o) mp[o] = ha * wm0[o] + hb * wm1[o];
#pragma unroll
    for (int s = 1; s < 64; s <<= 1) {
#pragma unroll
      for (int o = 0; o < 5; ++o) tl[o] += __shfl_xor(tl[o], s);
#pragma unroll
      for (int o = 0; o < 4; ++o) il[o] += __shfl_xor(il[o], s);
#pragma unroll
      for (int o = 0; o < 3; ++o) mp[o] += __shfl_xor(mp[o], s);
    }
    float t_[5], tp[5];
#pragma unroll
    for (int o = 0; o < 5; ++o) {
      t_[o] = tl[o] + btv[o];
      tp[o] = 1.f / (1.f + __expf(-t_[o]));
    }
    float i_[4];
#pragma unroll
    for (int o = 0; o < 4; ++o) i_[o] = il[o] + biv[o];
    float mx = fmaxf(fmaxf(i_[0], i_[1]), fmaxf(i_[2], i_[3]));
    float ex[4], es = 0.f;
#pragma unroll
    for (int o = 0; o < 4; ++o) { ex[o] = __expf(i_[o] - mx); es += ex[o]; }
    float inv_es = 1.f / es;
    float ml[3];
#pragma unroll
    for (int o = 0; o < 3; ++o) {
      float v = mp[o] + bmv[o];
#pragma unroll
      for (int j = 0; j < 5; ++j) v += tp[j] * wmt[j][o];
#pragma unroll
      for (int j = 0; j < 4; ++j) v += (ex[j] * inv_es) * wmi[j][o];
      ml[o] = v;
    }
    if (lane < 5) out_t[(size_t)row * 5 + lane] = t_[lane];
    else if (lane < 9) out_i[(size_t)row * 4 + (lane - 5)] = i_[lane - 5];
    else if (lane < 12) out_m[(size_t)row * 3 + (lane - 9)] = ml[lane - 9];
  }
}

// ------------------------------------------------------------------
extern "C" void kernel_launch(void* const* d_in, const int* in_sizes, int n_in,
                              void* d_out, int out_size, void* d_ws, size_t ws_size,
                              hipStream_t stream) {
  const float* x_comment = (const float*)d_in[0];
  const float* x_topic   = (const float*)d_in[1];
  const float* x_claim   = (const float*)d_in[2];
  const float* c1s_Wl = (const float*)d_in[3];
  const float* c1s_bl = (const float*)d_in[4];
  const float* c1s_Wr = (const float*)d_in[5];
  const float* c1a_Wl = (const float*)d_in[6];
  const float* c1a_bl = (const float*)d_in[7];
  const float* c1a_Wr = (const float*)d_in[8];
  const float* c1t_Wl = (const float*)d_in[9];
  const float* c1t_bl = (const float*)d_in[10];
  const float* c1t_Wr = (const float*)d_in[11];
  const float* c2s_Wl = (const float*)d_in[12];
  const float* c2s_bl = (const float*)d_in[13];
  const float* c2s_Wr = (const float*)d_in[14];
  const float* c2a_Wl = (const float*)d_in[15];
  const float* c2a_bl = (const float*)d_in[16];
  const float* c2a_Wr = (const float*)d_in[17];
  const float* c2t_Wl = (const float*)d_in[18];
  const float* c2t_bl = (const float*)d_in[19];
  const float* c2t_Wr = (const float*)d_in[20];
  const float* Wt = (const float*)d_in[21];
  const float* bt = (const float*)d_in[22];
  const float* Wi = (const float*)d_in[23];
  const float* bi = (const float*)d_in[24];
  const float* Wm = (const float*)d_in[25];
  const float* bm = (const float*)d_in[26];
  const int* ei_sim = (const int*)d_in[27];
  const int* ei_ab  = (const int*)d_in[28];
  const int* ei_tg  = (const int*)d_in[29];

  const int E_sim = in_sizes[27] / 2;
  const int E_ab  = in_sizes[28] / 2;
  const int E_tg  = in_sizes[29] / 2;
  const int N_T = in_sizes[1] / 128;
  const int N_CL = in_sizes[2] / 128;

  float* ws = (float*)d_ws;
  // workspace (float-element offsets; total ~23.1M floats = 92 MB)
  float* h1 = ws;                                    // 12.8M fp32 (h2 in-place)
  unsigned short* y_s = (unsigned short*)(ws + 12800000);  // 100000*128 bf16
  unsigned short* y_a = (unsigned short*)(ws + 19200000);  // 5000*128 bf16
  unsigned short* y_t = (unsigned short*)(ws + 19520000);  // 20000*128 bf16
  int*   cnt   = (int*)(ws + 20800000);
  float* inv   = ws + 21100000;
  int*   rs_s  = (int*)(ws + 21400000);
  int*   rs_a  = (int*)(ws + 21510000);
  int*   rs_t  = (int*)(ws + 21620000);
  int*   src_s = (int*)(ws + 21730000);
  int*   src_a = (int*)(ws + 22330000);
  int*   src_t = (int*)(ws + 22630000);
  int*   part  = (int*)(ws + 22930000);
  float* b1s   = ws + 22931600;
  float* b2s   = ws + 22931760;
  unsigned short* Bt_c1s = (unsigned short*)(ws + 22932000);  // 128x256
  unsigned short* Bt_W1s = Bt_c1s + 32768;                    // 128x256
  unsigned short* Bt_c1a = Bt_W1s + 32768;                    // 128x128
  unsigned short* Bt_c1t = Bt_c1a + 16384;
  unsigned short* Bt_c2s = Bt_c1t + 16384;
  unsigned short* Bt_W2s = Bt_c2s + 16384;
  unsigned short* Bt_c2a = Bt_W2s + 16384;
  unsigned short* Bt_c2t = Bt_c2a + 16384;

  const int nbS = (N_C + SCAN_CHUNK - 1) / SCAN_CHUNK;

  // ---- degree histogram + inverse ----
  hipMemsetAsync(cnt, 0, 3 * N_C * sizeof(int), stream);
  count_kernel<<<(E_sim + 255) / 256, 256, 0, stream>>>(ei_sim, cnt, E_sim);
  count_kernel<<<(E_ab + 255) / 256, 256, 0, stream>>>(ei_ab, cnt + N_C, E_ab);
  count_kernel<<<(E_tg + 255) / 256, 256, 0, stream>>>(ei_tg, cnt + 2 * N_C, E_tg);
  inv_kernel<<<(3 * N_C + 255) / 256, 256, 0, stream>>>(cnt, inv, 3 * N_C);

  // ---- CSR build ----
  scan_phaseA<<<nbS, 256, 0, stream>>>(cnt, part, N_C);
  scan_phaseB<<<1, 256, 0, stream>>>(part, nbS);
  scan_phaseC<<<nbS, 256, 0, stream>>>(cnt, part, rs_s, N_C);
  scan_phaseA<<<nbS, 256, 0, stream>>>(cnt + N_C, part + 128, N_C);
  scan_phaseB<<<1, 256, 0, stream>>>(part + 128, nbS);
  scan_phaseC<<<nbS, 256, 0, stream>>>(cnt + N_C, part + 128, rs_a, N_C);
  scan_phaseA<<<nbS, 256, 0, stream>>>(cnt + 2 * N_C, part + 256, N_C);
  scan_phaseB<<<1, 256, 0, stream>>>(part + 256, nbS);
  scan_phaseC<<<nbS, 256, 0, stream>>>(cnt + 2 * N_C, part + 256, rs_t, N_C);
  set_totals<<<1, 64, 0, stream>>>(rs_s, E_sim, rs_a, E_ab, rs_t, E_tg, N_C);

  hipMemsetAsync(cnt, 0, 3 * N_C * sizeof(int), stream);
  place_kernel<<<(E_sim + 255) / 256, 256, 0, stream>>>(ei_sim, rs_s, cnt, src_s, E_sim);
  place_kernel<<<(E_ab + 255) / 256, 256, 0, stream>>>(ei_ab, rs_a, cnt + N_C, src_a, E_ab);
  place_kernel<<<(E_tg + 255) / 256, 256, 0, stream>>>(ei_tg, rs_t, cnt + 2 * N_C, src_t, E_tg);

  // ---- weight prep: bf16 transposed B's, fp32 bias sums ----
  tcvt_kernel<<<(256 * 128 + 255) / 256, 256, 0, stream>>>(c1s_Wl, Bt_c1s, 256);
  tcvt3_kernel<<<(256 * 128 + 255) / 256, 256, 0, stream>>>(c1s_Wr, c1a_Wr, c1t_Wr, Bt_W1s, 256);
  tcvt_kernel<<<(128 * 128 + 255) / 256, 256, 0, stream>>>(c1a_Wl, Bt_c1a, 128);
  tcvt_kernel<<<(128 * 128 + 255) / 256, 256, 0, stream>>>(c1t_Wl, Bt_c1t, 128);
  tcvt_kernel<<<(128 * 128 + 255) / 256, 256, 0, stream>>>(c2s_Wl, Bt_c2s, 128);
  tcvt3_kernel<<<(128 * 128 + 255) / 256, 256, 0, stream>>>(c2s_Wr, c2a_Wr, c2t_Wr, Bt_W2s, 128);
  tcvt_kernel<<<(128 * 128 + 255) / 256, 256, 0, stream>>>(c2a_Wl, Bt_c2a, 128);
  tcvt_kernel<<<(128 * 128 + 255) / 256, 256, 0, stream>>>(c2t_Wl, Bt_c2t, 128);
  add3_kernel<<<1, 256, 0, stream>>>(c1s_bl, c1a_bl, c1t_bl, b1s, 128);
  add3_kernel<<<1, 256, 0, stream>>>(c2s_bl, c2a_bl, c2t_bl, b2s, 128);

  // ---------------- layer 1 ----------------
  mfma_gemm<256, true, false><<<(N_C + 127) / 128, 256, 0, stream>>>(
      x_comment, N_C, Bt_c1s, Bt_W1s, y_s, h1, b1s);
  mfma_gemm<128, false, false><<<(N_T + 127) / 128, 256, 0, stream>>>(
      x_topic, N_T, Bt_c1a, nullptr, y_a, nullptr, nullptr);
  mfma_gemm<128, false, false><<<(N_CL + 127) / 128, 256, 0, stream>>>(
      x_claim, N_CL, Bt_c1t, nullptr, y_t, nullptr, nullptr);

  gather_kernel<<<(N_C + 3) / 4, 256, 0, stream>>>(
      y_s, y_a, y_t, rs_s, src_s, rs_a, src_a, rs_t, src_t, inv, h1, N_C);

  // ---------------- layer 2 (in-place h1 -> h2) ----------------
  mfma_gemm<128, true, true><<<(N_C + 127) / 128, 256, 0, stream>>>(
      h1, N_C, Bt_c2s, Bt_W2s, y_s, h1, b2s);
  mfma_gemm<128, false, false><<<(N_T + 127) / 128, 256, 0, stream>>>(
      x_topic, N_T, Bt_c2a, nullptr, y_a, nullptr, nullptr);
  mfma_gemm<128, false, false><<<(N_CL + 127) / 128, 256, 0, stream>>>(
      x_claim, N_CL, Bt_c2t, nullptr, y_t, nullptr, nullptr);

  gather_kernel<<<(N_C + 3) / 4, 256, 0, stream>>>(
      y_s, y_a, y_t, rs_s, src_s, rs_a, src_a, rs_t, src_t, inv, h1, N_C);

  // ---------------- heads ----------------
  float* out = (float*)d_out;
  heads_kernel<<<1024, 256, 0, stream>>>(
      h1, Wt, bt, Wi, bi, Wm, bm,
      out, out + (size_t)N_C * 5, out + (size_t)N_C * 9, N_C);
}

// Round 4
// 673.679 us; speedup vs baseline: 6.9563x; 1.2674x over previous
//
#include <hip/hip_runtime.h>
#include <math.h>

#define N_C 100000
#define HD 128
#define SCAN_CHUNK 1024

typedef short v8s __attribute__((ext_vector_type(8)));
typedef float v4f __attribute__((ext_vector_type(4)));

__device__ __forceinline__ unsigned short f2bf(float f) {
  unsigned int u = __float_as_uint(f);
  u += 0x7fffu + ((u >> 16) & 1u);
  return (unsigned short)(u >> 16);
}

// ------------------------------------------------------------------
// fused prep kernels (batched over blockIdx.y)
// ------------------------------------------------------------------
__global__ void count3_kernel(const int* __restrict__ ei_s, int Es,
                              const int* __restrict__ ei_a, int Ea,
                              const int* __restrict__ ei_t, int Et,
                              int* __restrict__ cnt) {
  int e = blockIdx.x * 256 + threadIdx.x;
  int y = blockIdx.y;
  if (y == 0) {
    if (e < Es) atomicAdd(&cnt[ei_s[Es + e]], 1);
  } else if (y == 1) {
    if (e < Ea) atomicAdd(&cnt[N_C + ei_a[Ea + e]], 1);
  } else {
    if (e < Et) atomicAdd(&cnt[2 * N_C + ei_t[Et + e]], 1);
  }
}

__global__ void place3_kernel(const int* __restrict__ ei_s, int Es,
                              const int* __restrict__ ei_a, int Ea,
                              const int* __restrict__ ei_t, int Et,
                              const int* __restrict__ rs_all, int* __restrict__ fill,
                              int* __restrict__ src_s, int* __restrict__ src_a,
                              int* __restrict__ src_t, int n) {
  int e = blockIdx.x * 256 + threadIdx.x;
  int y = blockIdx.y;
  const int* ei; int E; const int* rs; int* fl; int* out;
  if (y == 0)      { ei = ei_s; E = Es; rs = rs_all;               fl = fill;         out = src_s; }
  else if (y == 1) { ei = ei_a; E = Ea; rs = rs_all + (n + 1);     fl = fill + n;     out = src_a; }
  else             { ei = ei_t; E = Et; rs = rs_all + 2 * (n + 1); fl = fill + 2 * n; out = src_t; }
  if (e < E) {
    int d = ei[E + e];
    int p = rs[d] + atomicAdd(&fl[d], 1);
    out[p] = ei[e];
  }
}

// ------------------------------------------------------------------
// 3-phase exclusive scan, batched over 3 arrays via blockIdx.y
// phaseA also emits inv = 1/max(cnt,1)
// ------------------------------------------------------------------
__global__ __launch_bounds__(256) void scan_phaseA(const int* __restrict__ cnt,
                                                   int* __restrict__ partial,
                                                   float* __restrict__ inv, int n) {
  __shared__ int sdata[256];
  const int y = blockIdx.y;
  const int* c = cnt + y * n;
  float* iv = inv + y * n;
  int base = blockIdx.x * SCAN_CHUNK + threadIdx.x * 4;
  int s = 0;
#pragma unroll
  for (int j = 0; j < 4; ++j) {
    int idx = base + j;
    if (idx < n) {
      int v = c[idx];
      s += v;
      iv[idx] = 1.0f / fmaxf((float)v, 1.0f);
    }
  }
  sdata[threadIdx.x] = s;
  __syncthreads();
  for (int off = 128; off > 0; off >>= 1) {
    if (threadIdx.x < off) sdata[threadIdx.x] += sdata[threadIdx.x + off];
    __syncthreads();
  }
  if (threadIdx.x == 0) partial[y * 128 + blockIdx.x] = sdata[0];
}

__global__ __launch_bounds__(256) void scan_phaseB(int* __restrict__ partial, int nb) {
  __shared__ int sdata[256];
  int* p = partial + blockIdx.y * 128;
  int t = threadIdx.x;
  int v = (t < nb) ? p[t] : 0;
  sdata[t] = v;
  __syncthreads();
  for (int off = 1; off < 256; off <<= 1) {
    int x = (t >= off) ? sdata[t - off] : 0;
    __syncthreads();
    sdata[t] += x;
    __syncthreads();
  }
  if (t < nb) p[t] = sdata[t] - v;
}

__global__ __launch_bounds__(256) void scan_phaseC(const int* __restrict__ cnt,
                                                   const int* __restrict__ partial,
                                                   int* __restrict__ rs_all, int n) {
  __shared__ int sdata[256];
  const int y = blockIdx.y;
  const int* c = cnt + y * n;
  int* rs = rs_all + y * (n + 1);
  int t = threadIdx.x;
  int base = blockIdx.x * SCAN_CHUNK + t * 4;
  int v[4];
  int s = 0;
#pragma unroll
  for (int j = 0; j < 4; ++j) {
    int idx = base + j;
    v[j] = (idx < n) ? c[idx] : 0;
    s += v[j];
  }
  sdata[t] = s;
  __syncthreads();
  for (int off = 1; off < 256; off <<= 1) {
    int x = (t >= off) ? sdata[t - off] : 0;
    __syncthreads();
    sdata[t] += x;
    __syncthreads();
  }
  int run = sdata[t] - s + partial[y * 128 + blockIdx.x];
#pragma unroll
  for (int j = 0; j < 4; ++j) {
    int idx = base + j;
    if (idx < n) rs[idx] = run;
    run += v[j];
  }
}

__global__ void set_totals(int* rs_all, int Es, int Ea, int Et, int n) {
  if (threadIdx.x == 0) {
    rs_all[n] = Es;
    rs_all[(n + 1) + n] = Ea;
    rs_all[2 * (n + 1) + n] = Et;
  }
}

// ------------------------------------------------------------------
// single prep kernel: 8 weight transposes+cvt (y=0..7), bias sums (y=8)
// grid (128, 9) x 256
// ------------------------------------------------------------------
__global__ void prep_weights(
    const float* __restrict__ c1s_Wl, const float* __restrict__ c1s_Wr,
    const float* __restrict__ c1a_Wr, const float* __restrict__ c1t_Wr,
    const float* __restrict__ c1a_Wl, const float* __restrict__ c1t_Wl,
    const float* __restrict__ c2s_Wl, const float* __restrict__ c2s_Wr,
    const float* __restrict__ c2a_Wr, const float* __restrict__ c2t_Wr,
    const float* __restrict__ c2a_Wl, const float* __restrict__ c2t_Wl,
    const float* __restrict__ c1s_bl, const float* __restrict__ c1a_bl,
    const float* __restrict__ c1t_bl, const float* __restrict__ c2s_bl,
    const float* __restrict__ c2a_bl, const float* __restrict__ c2t_bl,
    unsigned short* __restrict__ Bt_c1s, unsigned short* __restrict__ Bt_W1s,
    unsigned short* __restrict__ Bt_c1a, unsigned short* __restrict__ Bt_c1t,
    unsigned short* __restrict__ Bt_c2s, unsigned short* __restrict__ Bt_W2s,
    unsigned short* __restrict__ Bt_c2a, unsigned short* __restrict__ Bt_c2t,
    float* __restrict__ b1s, float* __restrict__ b2s) {
  int y = blockIdx.y;
  int idx = blockIdx.x * 256 + threadIdx.x;
  if (y == 8) {
    if (blockIdx.x == 0) {
      int t = threadIdx.x;
      if (t < 128) b1s[t] = c1s_bl[t] + c1a_bl[t] + c1t_bl[t];
      else b2s[t - 128] = c2s_bl[t - 128] + c2a_bl[t - 128] + c2t_bl[t - 128];
    }
    return;
  }
  int K = (y < 2) ? 256 : 128;
  if (idx >= K * 128) return;
  int k = idx >> 7, n = idx & 127;
  float v;
  unsigned short* out;
  switch (y) {
    case 0: v = c1s_Wl[idx]; out = Bt_c1s; break;
    case 1: v = c1s_Wr[idx] + c1a_Wr[idx] + c1t_Wr[idx]; out = Bt_W1s; break;
    case 2: v = c1a_Wl[idx]; out = Bt_c1a; break;
    case 3: v = c1t_Wl[idx]; out = Bt_c1t; break;
    case 4: v = c2s_Wl[idx]; out = Bt_c2s; break;
    case 5: v = c2s_Wr[idx] + c2a_Wr[idx] + c2t_Wr[idx]; out = Bt_W2s; break;
    case 6: v = c2a_Wl[idx]; out = Bt_c2a; break;
    default: v = c2t_Wl[idx]; out = Bt_c2t; break;
  }
  out[n * K + k] = f2bf(v);
}

// ------------------------------------------------------------------
// MFMA GEMM: C0(bf16) = act(A)@B0 [, C1(fp32) = act(A)@B1 + bias1]
// tile 128x128, 4 waves 2x2, BK=64, mfma 16x16x32 bf16
// A/C1 not __restrict__ — layer-2 call runs in-place (C1 == A).
// ------------------------------------------------------------------
template <int KD, bool DUAL, bool RELUA>
__global__ __launch_bounds__(256, 2) void mfma_gemm(
    const float* A, int M,
    const unsigned short* __restrict__ B0t, const unsigned short* __restrict__ B1t,
    unsigned short* __restrict__ C0, float* C1, const float* __restrict__ bias1) {
  constexpr int AST = 72;
  __shared__ unsigned short As[128 * AST];
  __shared__ unsigned short Bs0[128 * AST];
  __shared__ unsigned short Bs1[DUAL ? 128 * AST : 8];

  const int t = threadIdx.x;
  const int wave = t >> 6, lane = t & 63;
  const int wm = (wave & 1) * 64;
  const int wn = (wave >> 1) * 64;
  const int m0 = blockIdx.x * 128;
  const int lrow = lane & 15, lq = lane >> 4;

  v4f acc0[4][4];
  v4f acc1[DUAL ? 4 : 1][DUAL ? 4 : 1];
#pragma unroll
  for (int i = 0; i < 4; ++i)
#pragma unroll
    for (int j = 0; j < 4; ++j) acc0[i][j] = (v4f)(0.f);
  if constexpr (DUAL) {
#pragma unroll
    for (int i = 0; i < 4; ++i)
#pragma unroll
      for (int j = 0; j < 4; ++j) acc1[i][j] = (v4f)(0.f);
  }

  for (int k0 = 0; k0 < KD; k0 += 64) {
#pragma unroll
    for (int j = 0; j < 8; ++j) {
      int idx = j * 256 + t;
      int row = idx >> 4;
      int c4 = idx & 15;
      int gr = m0 + row;
      float4 v = make_float4(0.f, 0.f, 0.f, 0.f);
      if (gr < M) v = *(const float4*)(A + (size_t)gr * KD + k0 + c4 * 4);
      if (RELUA) {
        v.x = fmaxf(v.x, 0.f); v.y = fmaxf(v.y, 0.f);
        v.z = fmaxf(v.z, 0.f); v.w = fmaxf(v.w, 0.f);
      }
      unsigned short* d = &As[row * AST + c4 * 4];
      d[0] = f2bf(v.x); d[1] = f2bf(v.y); d[2] = f2bf(v.z); d[3] = f2bf(v.w);
    }
#pragma unroll
    for (int j = 0; j < 4; ++j) {
      int idx = j * 256 + t;
      int row = idx >> 3;
      int k8 = idx & 7;
      uint4 v = *(const uint4*)(B0t + (size_t)row * KD + k0 + k8 * 8);
      *(uint4*)&Bs0[row * AST + k8 * 8] = v;
      if constexpr (DUAL) {
        uint4 w = *(const uint4*)(B1t + (size_t)row * KD + k0 + k8 * 8);
        *(uint4*)&Bs1[row * AST + k8 * 8] = w;
      }
    }
    __syncthreads();

#pragma unroll
    for (int ks = 0; ks < 2; ++ks) {
      v8s af[4];
#pragma unroll
      for (int mt = 0; mt < 4; ++mt)
        af[mt] = *(const v8s*)&As[(wm + mt * 16 + lrow) * AST + ks * 32 + lq * 8];
#pragma unroll
      for (int cb = 0; cb < 4; ++cb) {
        v8s b0 = *(const v8s*)&Bs0[(wn + cb * 16 + lrow) * AST + ks * 32 + lq * 8];
#pragma unroll
        for (int mt = 0; mt < 4; ++mt)
          acc0[mt][cb] = __builtin_amdgcn_mfma_f32_16x16x32_bf16(af[mt], b0, acc0[mt][cb], 0, 0, 0);
        if constexpr (DUAL) {
          v8s b1 = *(const v8s*)&Bs1[(wn + cb * 16 + lrow) * AST + ks * 32 + lq * 8];
#pragma unroll
          for (int mt = 0; mt < 4; ++mt)
            acc1[mt][cb] = __builtin_amdgcn_mfma_f32_16x16x32_bf16(af[mt], b1, acc1[mt][cb], 0, 0, 0);
        }
      }
    }
    __syncthreads();
  }

  float bv[4] = {0.f, 0.f, 0.f, 0.f};
  if constexpr (DUAL) {
#pragma unroll
    for (int cb = 0; cb < 4; ++cb) bv[cb] = bias1[wn + cb * 16 + lrow];
  }
#pragma unroll
  for (int mt = 0; mt < 4; ++mt) {
#pragma unroll
    for (int r = 0; r < 4; ++r) {
      int gr = m0 + wm + mt * 16 + lq * 4 + r;
      if (gr < M) {
#pragma unroll
        for (int cb = 0; cb < 4; ++cb) {
          int gc = wn + cb * 16 + lrow;
          C0[(size_t)gr * 128 + gc] = f2bf(acc0[mt][cb][r]);
          if constexpr (DUAL) C1[(size_t)gr * 128 + gc] = acc1[mt][cb][r] + bv[cb];
        }
      }
    }
  }
}

// ------------------------------------------------------------------
// fused CSR gather, quarter-wave per edge: 16 lanes x uint4 (8 bf16)
// cover a 256B row in ONE load -> 4 edges in flight per wave.
// Cross-quarter shfl reduction, single RMW write by quarter 0.
// ------------------------------------------------------------------
__global__ __launch_bounds__(256) void gather_kernel(
    const unsigned short* __restrict__ ys, const unsigned short* __restrict__ ya,
    const unsigned short* __restrict__ yt,
    const int* __restrict__ rs_all,
    const int* __restrict__ src_s, const int* __restrict__ src_a,
    const int* __restrict__ src_t,
    const float* __restrict__ inv, float* h, int M) {
  int row = blockIdx.x * 4 + (threadIdx.x >> 6);
  if (row >= M) return;
  const int lane = threadIdx.x & 63;
  const int q = lane >> 4;
  const int col = (lane & 15) * 8;
  const int NP = M + 1;

  int b0 = rs_all[row],          e0 = rs_all[row + 1];
  int b1 = rs_all[NP + row],     e1 = rs_all[NP + row + 1];
  int b2 = rs_all[2 * NP + row], e2 = rs_all[2 * NP + row + 1];
  float sc0 = inv[row], sc1 = inv[M + row], sc2 = inv[2 * M + row];

  float acc[8];
#pragma unroll
  for (int j = 0; j < 8; ++j) acc[j] = 0.f;

  auto seg = [&](const unsigned short* __restrict__ y, const int* __restrict__ src,
                 int b, int e, float sc) {
    float s[8];
#pragma unroll
    for (int j = 0; j < 8; ++j) s[j] = 0.f;
    for (int i = b + q; i < e; i += 4) {
      int si = src[i];
      uint4 v = *(const uint4*)(y + (size_t)si * HD + col);
      s[0] += __uint_as_float(v.x << 16);
      s[1] += __uint_as_float(v.x & 0xffff0000u);
      s[2] += __uint_as_float(v.y << 16);
      s[3] += __uint_as_float(v.y & 0xffff0000u);
      s[4] += __uint_as_float(v.z << 16);
      s[5] += __uint_as_float(v.z & 0xffff0000u);
      s[6] += __uint_as_float(v.w << 16);
      s[7] += __uint_as_float(v.w & 0xffff0000u);
    }
#pragma unroll
    for (int j = 0; j < 8; ++j) acc[j] += s[j] * sc;
  };
  seg(ys, src_s, b0, e0, sc0);
  seg(ya, src_a, b1, e1, sc1);
  seg(yt, src_t, b2, e2, sc2);

#pragma unroll
  for (int j = 0; j < 8; ++j) {
    acc[j] += __shfl_xor(acc[j], 16);
    acc[j] += __shfl_xor(acc[j], 32);
  }
  if (q == 0) {
    float4* hp = (float4*)(h + (size_t)row * HD + col);
    float4 a = hp[0], b = hp[1];
    a.x += acc[0]; a.y += acc[1]; a.z += acc[2]; a.w += acc[3];
    b.x += acc[4]; b.y += acc[5]; b.z += acc[6]; b.w += acc[7];
    hp[0] = a; hp[1] = b;
  }
}

// ------------------------------------------------------------------
// heads
// ------------------------------------------------------------------
__global__ __launch_bounds__(256) void heads_kernel(
    const float* __restrict__ h2,
    const float* __restrict__ Wt, const float* __restrict__ bt,
    const float* __restrict__ Wi, const float* __restrict__ bi,
    const float* __restrict__ Wm, const float* __restrict__ bm,
    float* __restrict__ out_t, float* __restrict__ out_i,
    float* __restrict__ out_m, int M) {
  const int lane = threadIdx.x & 63;
  const int wave = (blockIdx.x * blockDim.x + threadIdx.x) >> 6;
  const int nw = (gridDim.x * blockDim.x) >> 6;
  const int k0 = lane * 2;

  float wt0[5], wt1[5];
#pragma unroll
  for (int o = 0; o < 5; ++o) { wt0[o] = Wt[k0 * 5 + o]; wt1[o] = Wt[(k0 + 1) * 5 + o]; }
  float wi0[4], wi1[4];
#pragma unroll
  for (int o = 0; o < 4; ++o) { wi0[o] = Wi[k0 * 4 + o]; wi1[o] = Wi[(k0 + 1) * 4 + o]; }
  float wm0[3], wm1[3];
#pragma unroll
  for (int o = 0; o < 3; ++o) { wm0[o] = Wm[k0 * 3 + o]; wm1[o] = Wm[(k0 + 1) * 3 + o]; }
  float btv[5], biv[4], bmv[3];
#pragma unroll
  for (int o = 0; o < 5; ++o) btv[o] = bt[o];
#pragma unroll
  for (int o = 0; o < 4; ++o) biv[o] = bi[o];
#pragma unroll
  for (int o = 0; o < 3; ++o) bmv[o] = bm[o];
  float wmt[5][3], wmi[4][3];
#pragma unroll
  for (int j = 0; j < 5; ++j)
#pragma unroll
    for (int o = 0; o < 3; ++o) wmt[j][o] = Wm[(128 + j) * 3 + o];
#pragma unroll
  for (int j = 0; j < 4; ++j)
#pragma unroll
    for (int o = 0; o < 3; ++o) wmi[j][o] = Wm[(133 + j) * 3 + o];

  for (int row = wave; row < M; row += nw) {
    float2 hv = *(const float2*)(h2 + (size_t)row * 128 + k0);
    float ha = fmaxf(hv.x, 0.f), hb = fmaxf(hv.y, 0.f);
    float tl[5], il[4], mp[3];
#pragma unroll
    for (int o = 0; o < 5; ++o) tl[o] = ha * wt0[o] + hb * wt1[o];
#pragma unroll
    for (int o = 0; o < 4; ++o) il[o] = ha * wi0[o] + hb * wi1[o];
#pragma unroll
    for (int o = 0; o < 3; ++o) mp[o] = ha * wm0[o] + hb * wm1[o];
#pragma unroll
    for (int s = 1; s < 64; s <<= 1) {
#pragma unroll
      for (int o = 0; o < 5; ++o) tl[o] += __shfl_xor(tl[o], s);
#pragma unroll
      for (int o = 0; o < 4; ++o) il[o] += __shfl_xor(il[o], s);
#pragma unroll
      for (int o = 0; o < 3; ++o) mp[o] += __shfl_xor(mp[o], s);
    }
    float t_[5], tp[5];
#pragma unroll
    for (int o = 0; o < 5; ++o) {
      t_[o] = tl[o] + btv[o];
      tp[o] = 1.f / (1.f + __expf(-t_[o]));
    }
    float i_[4];
#pragma unroll
    for (int o = 0; o < 4; ++o) i_[o] = il[o] + biv[o];
    float mx = fmaxf(fmaxf(i_[0], i_[1]), fmaxf(i_[2], i_[3]));
    float ex[4], es = 0.f;
#pragma unroll
    for (int o = 0; o < 4; ++o) { ex[o] = __expf(i_[o] - mx); es += ex[o]; }
    float inv_es = 1.f / es;
    float ml[3];
#pragma unroll
    for (int o = 0; o < 3; ++o) {
      float v = mp[o] + bmv[o];
#pragma unroll
      for (int j = 0; j < 5; ++j) v += tp[j] * wmt[j][o];
#pragma unroll
      for (int j = 0; j < 4; ++j) v += (ex[j] * inv_es) * wmi[j][o];
      ml[o] = v;
    }
    if (lane < 5) out_t[(size_t)row * 5 + lane] = t_[lane];
    else if (lane < 9) out_i[(size_t)row * 4 + (lane - 5)] = i_[lane - 5];
    else if (lane < 12) out_m[(size_t)row * 3 + (lane - 9)] = ml[lane - 9];
  }
}

// ------------------------------------------------------------------
extern "C" void kernel_launch(void* const* d_in, const int* in_sizes, int n_in,
                              void* d_out, int out_size, void* d_ws, size_t ws_size,
                              hipStream_t stream) {
  const float* x_comment = (const float*)d_in[0];
  const float* x_topic   = (const float*)d_in[1];
  const float* x_claim   = (const float*)d_in[2];
  const float* c1s_Wl = (const float*)d_in[3];
  const float* c1s_bl = (const float*)d_in[4];
  const float* c1s_Wr = (const float*)d_in[5];
  const float* c1a_Wl = (const float*)d_in[6];
  const float* c1a_bl = (const float*)d_in[7];
  const float* c1a_Wr = (const float*)d_in[8];
  const float* c1t_Wl = (const float*)d_in[9];
  const float* c1t_bl = (const float*)d_in[10];
  const float* c1t_Wr = (const float*)d_in[11];
  const float* c2s_Wl = (const float*)d_in[12];
  const float* c2s_bl = (const float*)d_in[13];
  const float* c2s_Wr = (const float*)d_in[14];
  const float* c2a_Wl = (const float*)d_in[15];
  const float* c2a_bl = (const float*)d_in[16];
  const float* c2a_Wr = (const float*)d_in[17];
  const float* c2t_Wl = (const float*)d_in[18];
  const float* c2t_bl = (const float*)d_in[19];
  const float* c2t_Wr = (const float*)d_in[20];
  const float* Wt = (const float*)d_in[21];
  const float* bt = (const float*)d_in[22];
  const float* Wi = (const float*)d_in[23];
  const float* bi = (const float*)d_in[24];
  const float* Wm = (const float*)d_in[25];
  const float* bm = (const float*)d_in[26];
  const int* ei_sim = (const int*)d_in[27];
  const int* ei_ab  = (const int*)d_in[28];
  const int* ei_tg  = (const int*)d_in[29];

  const int E_sim = in_sizes[27] / 2;
  const int E_ab  = in_sizes[28] / 2;
  const int E_tg  = in_sizes[29] / 2;
  const int N_T = in_sizes[1] / 128;
  const int N_CL = in_sizes[2] / 128;

  float* ws = (float*)d_ws;
  // workspace (float-element offsets)
  float* h1 = ws;                                          // 12.8M fp32
  unsigned short* y_s = (unsigned short*)(ws + 12800000);  // 100000*128 bf16
  unsigned short* y_a = (unsigned short*)(ws + 19200000);  // 5000*128 bf16
  unsigned short* y_t = (unsigned short*)(ws + 19520000);  // 20000*128 bf16
  int*   cnt    = (int*)(ws + 20800000);                   // 3*N_C
  float* inv    = ws + 21100000;                           // 3*N_C
  int*   rs_all = (int*)(ws + 21400000);                   // 3*(N_C+1)
  int*   src_s  = (int*)(ws + 21700016);                   // E_sim
  int*   src_a  = (int*)(ws + 22300016);                   // E_ab
  int*   src_t  = (int*)(ws + 22600016);                   // E_tg
  int*   part   = (int*)(ws + 22900016);                   // 3*128
  float* b1s    = ws + 22900416;
  float* b2s    = ws + 22900544;
  unsigned short* Bt_c1s = (unsigned short*)(ws + 22900672);  // 128x256
  unsigned short* Bt_W1s = Bt_c1s + 32768;                    // 128x256
  unsigned short* Bt_c1a = Bt_W1s + 32768;                    // 128x128
  unsigned short* Bt_c1t = Bt_c1a + 16384;
  unsigned short* Bt_c2s = Bt_c1t + 16384;
  unsigned short* Bt_W2s = Bt_c2s + 16384;
  unsigned short* Bt_c2a = Bt_W2s + 16384;
  unsigned short* Bt_c2t = Bt_c2a + 16384;

  const int nbS = (N_C + SCAN_CHUNK - 1) / SCAN_CHUNK;
  const int ebx = (E_sim + 255) / 256;  // largest edge count

  // ---- weight prep (independent of graph work; launch first) ----
  prep_weights<<<dim3(128, 9), 256, 0, stream>>>(
      c1s_Wl, c1s_Wr, c1a_Wr, c1t_Wr, c1a_Wl, c1t_Wl,
      c2s_Wl, c2s_Wr, c2a_Wr, c2t_Wr, c2a_Wl, c2t_Wl,
      c1s_bl, c1a_bl, c1t_bl, c2s_bl, c2a_bl, c2t_bl,
      Bt_c1s, Bt_W1s, Bt_c1a, Bt_c1t, Bt_c2s, Bt_W2s, Bt_c2a, Bt_c2t,
      b1s, b2s);

  // ---- degree histogram + CSR build ----
  hipMemsetAsync(cnt, 0, 3 * N_C * sizeof(int), stream);
  count3_kernel<<<dim3(ebx, 3), 256, 0, stream>>>(ei_sim, E_sim, ei_ab, E_ab, ei_tg, E_tg, cnt);
  scan_phaseA<<<dim3(nbS, 3), 256, 0, stream>>>(cnt, part, inv, N_C);
  scan_phaseB<<<dim3(1, 3), 256, 0, stream>>>(part, nbS);
  scan_phaseC<<<dim3(nbS, 3), 256, 0, stream>>>(cnt, part, rs_all, N_C);
  set_totals<<<1, 64, 0, stream>>>(rs_all, E_sim, E_ab, E_tg, N_C);
  hipMemsetAsync(cnt, 0, 3 * N_C * sizeof(int), stream);  // reuse as fill
  place3_kernel<<<dim3(ebx, 3), 256, 0, stream>>>(
      ei_sim, E_sim, ei_ab, E_ab, ei_tg, E_tg, rs_all, cnt, src_s, src_a, src_t, N_C);

  // ---------------- layer 1 ----------------
  mfma_gemm<256, true, false><<<(N_C + 127) / 128, 256, 0, stream>>>(
      x_comment, N_C, Bt_c1s, Bt_W1s, y_s, h1, b1s);
  mfma_gemm<128, false, false><<<(N_T + 127) / 128, 256, 0, stream>>>(
      x_topic, N_T, Bt_c1a, nullptr, y_a, nullptr, nullptr);
  mfma_gemm<128, false, false><<<(N_CL + 127) / 128, 256, 0, stream>>>(
      x_claim, N_CL, Bt_c1t, nullptr, y_t, nullptr, nullptr);

  gather_kernel<<<(N_C + 3) / 4, 256, 0, stream>>>(
      y_s, y_a, y_t, rs_all, src_s, src_a, src_t, inv, h1, N_C);

  // ---------------- layer 2 (in-place h1 -> h2) ----------------
  mfma_gemm<128, true, true><<<(N_C + 127) / 128, 256, 0, stream>>>(
      h1, N_C, Bt_c2s, Bt_W2s, y_s, h1, b2s);
  mfma_gemm<128, false, false><<<(N_T + 127) / 128, 256, 0, stream>>>(
      x_topic, N_T, Bt_c2a, nullptr, y_a, nullptr, nullptr);
  mfma_gemm<128, false, false><<<(N_CL + 127) / 128, 256, 0, stream>>>(
      x_claim, N_CL, Bt_c2t, nullptr, y_t, nullptr, nullptr);

  gather_kernel<<<(N_C + 3) / 4, 256, 0, stream>>>(
      y_s, y_a, y_t, rs_all, src_s, src_a, src_t, inv, h1, N_C);

  // ---------------- heads ----------------
  float* out = (float*)d_out;
  heads_kernel<<<1024, 256, 0, stream>>>(
      h1, Wt, bt, Wi, bi, Wm, bm,
      out, out + (size_t)N_C * 5, out + (size_t)N_C * 9, N_C);
}

// Round 6
// 594.703 us; speedup vs baseline: 7.8801x; 1.1328x over previous
//
#include <hip/hip_runtime.h>
#include <math.h>

#define N_C 100000
#define HD 128
#define SCAN_CHUNK 1024

typedef short v8s __attribute__((ext_vector_type(8)));
typedef float v4f __attribute__((ext_vector_type(4)));

__device__ __forceinline__ unsigned short f2bf(float f) {
  unsigned int u = __float_as_uint(f);
  u += 0x7fffu + ((u >> 16) & 1u);
  return (unsigned short)(u >> 16);
}

// ------------------------------------------------------------------
// fused prep kernels (batched over blockIdx.y)
// ------------------------------------------------------------------
__global__ void count3_kernel(const int* __restrict__ ei_s, int Es,
                              const int* __restrict__ ei_a, int Ea,
                              const int* __restrict__ ei_t, int Et,
                              int* __restrict__ cnt) {
  int e = blockIdx.x * 256 + threadIdx.x;
  int y = blockIdx.y;
  if (y == 0) {
    if (e < Es) atomicAdd(&cnt[ei_s[Es + e]], 1);
  } else if (y == 1) {
    if (e < Ea) atomicAdd(&cnt[N_C + ei_a[Ea + e]], 1);
  } else {
    if (e < Et) atomicAdd(&cnt[2 * N_C + ei_t[Et + e]], 1);
  }
}

__global__ void place3_kernel(const int* __restrict__ ei_s, int Es,
                              const int* __restrict__ ei_a, int Ea,
                              const int* __restrict__ ei_t, int Et,
                              const int* __restrict__ rs_all, int* __restrict__ fill,
                              int* __restrict__ src_s, int* __restrict__ src_a,
                              int* __restrict__ src_t, int n) {
  int e = blockIdx.x * 256 + threadIdx.x;
  int y = blockIdx.y;
  const int* ei; int E; const int* rs; int* fl; int* out;
  if (y == 0)      { ei = ei_s; E = Es; rs = rs_all;               fl = fill;         out = src_s; }
  else if (y == 1) { ei = ei_a; E = Ea; rs = rs_all + (n + 1);     fl = fill + n;     out = src_a; }
  else             { ei = ei_t; E = Et; rs = rs_all + 2 * (n + 1); fl = fill + 2 * n; out = src_t; }
  if (e < E) {
    int d = ei[E + e];
    int p = rs[d] + atomicAdd(&fl[d], 1);
    out[p] = ei[e];
  }
}

// ------------------------------------------------------------------
// 3-phase exclusive scan, batched over 3 arrays via blockIdx.y
// phaseA also emits inv = 1/max(cnt,1)
// ------------------------------------------------------------------
__global__ __launch_bounds__(256) void scan_phaseA(const int* __restrict__ cnt,
                                                   int* __restrict__ partial,
                                                   float* __restrict__ inv, int n) {
  __shared__ int sdata[256];
  const int y = blockIdx.y;
  const int* c = cnt + y * n;
  float* iv = inv + y * n;
  int base = blockIdx.x * SCAN_CHUNK + threadIdx.x * 4;
  int s = 0;
#pragma unroll
  for (int j = 0; j < 4; ++j) {
    int idx = base + j;
    if (idx < n) {
      int v = c[idx];
      s += v;
      iv[idx] = 1.0f / fmaxf((float)v, 1.0f);
    }
  }
  sdata[threadIdx.x] = s;
  __syncthreads();
  for (int off = 128; off > 0; off >>= 1) {
    if (threadIdx.x < off) sdata[threadIdx.x] += sdata[threadIdx.x + off];
    __syncthreads();
  }
  if (threadIdx.x == 0) partial[y * 128 + blockIdx.x] = sdata[0];
}

__global__ __launch_bounds__(256) void scan_phaseB(int* __restrict__ partial, int nb) {
  __shared__ int sdata[256];
  int* p = partial + blockIdx.y * 128;
  int t = threadIdx.x;
  int v = (t < nb) ? p[t] : 0;
  sdata[t] = v;
  __syncthreads();
  for (int off = 1; off < 256; off <<= 1) {
    int x = (t >= off) ? sdata[t - off] : 0;
    __syncthreads();
    sdata[t] += x;
    __syncthreads();
  }
  if (t < nb) p[t] = sdata[t] - v;
}

__global__ __launch_bounds__(256) void scan_phaseC(const int* __restrict__ cnt,
                                                   const int* __restrict__ partial,
                                                   int* __restrict__ rs_all, int n) {
  __shared__ int sdata[256];
  const int y = blockIdx.y;
  const int* c = cnt + y * n;
  int* rs = rs_all + y * (n + 1);
  int t = threadIdx.x;
  int base = blockIdx.x * SCAN_CHUNK + t * 4;
  int v[4];
  int s = 0;
#pragma unroll
  for (int j = 0; j < 4; ++j) {
    int idx = base + j;
    v[j] = (idx < n) ? c[idx] : 0;
    s += v[j];
  }
  sdata[t] = s;
  __syncthreads();
  for (int off = 1; off < 256; off <<= 1) {
    int x = (t >= off) ? sdata[t - off] : 0;
    __syncthreads();
    sdata[t] += x;
    __syncthreads();
  }
  int run = sdata[t] - s + partial[y * 128 + blockIdx.x];
#pragma unroll
  for (int j = 0; j < 4; ++j) {
    int idx = base + j;
    if (idx < n) rs[idx] = run;
    run += v[j];
  }
}

__global__ void set_totals(int* rs_all, int Es, int Ea, int Et, int n) {
  if (threadIdx.x == 0) {
    rs_all[n] = Es;
    rs_all[(n + 1) + n] = Ea;
    rs_all[2 * (n + 1) + n] = Et;
  }
}

// ------------------------------------------------------------------
// single prep kernel: 8 weight transposes+cvt (y=0..7), biases (y=8),
// packed head weight [16 x 128] bf16 (y=9). grid (128, 10) x 256
// ------------------------------------------------------------------
__global__ void prep_weights(
    const float* __restrict__ c1s_Wl, const float* __restrict__ c1s_Wr,
    const float* __restrict__ c1a_Wr, const float* __restrict__ c1t_Wr,
    const float* __restrict__ c1a_Wl, const float* __restrict__ c1t_Wl,
    const float* __restrict__ c2s_Wl, const float* __restrict__ c2s_Wr,
    const float* __restrict__ c2a_Wr, const float* __restrict__ c2t_Wr,
    const float* __restrict__ c2a_Wl, const float* __restrict__ c2t_Wl,
    const float* __restrict__ c1s_bl, const float* __restrict__ c1a_bl,
    const float* __restrict__ c1t_bl, const float* __restrict__ c2s_bl,
    const float* __restrict__ c2a_bl, const float* __restrict__ c2t_bl,
    const float* __restrict__ Wt, const float* __restrict__ bt,
    const float* __restrict__ Wi, const float* __restrict__ bi,
    const float* __restrict__ Wm, const float* __restrict__ bm,
    unsigned short* __restrict__ Bt_c1s, unsigned short* __restrict__ Bt_W1s,
    unsigned short* __restrict__ Bt_c1a, unsigned short* __restrict__ Bt_c1t,
    unsigned short* __restrict__ Bt_c2s, unsigned short* __restrict__ Bt_W2s,
    unsigned short* __restrict__ Bt_c2a, unsigned short* __restrict__ Bt_c2t,
    unsigned short* __restrict__ Wht,
    float* __restrict__ b1s, float* __restrict__ b2s, float* __restrict__ bh) {
  int y = blockIdx.y;
  int idx = blockIdx.x * 256 + threadIdx.x;
  if (y == 8) {
    if (blockIdx.x == 0) {
      int t = threadIdx.x;
      if (t < 128) b1s[t] = c1s_bl[t] + c1a_bl[t] + c1t_bl[t];
      else b2s[t - 128] = c2s_bl[t - 128] + c2a_bl[t - 128] + c2t_bl[t - 128];
    } else if (blockIdx.x == 1) {
      int t = threadIdx.x;
      if (t < 16) {
        float v = 0.f;
        if (t < 5) v = bt[t];
        else if (t < 9) v = bi[t - 5];
        else if (t < 12) v = bm[t - 9];
        bh[t] = v;
      }
    }
    return;
  }
  if (y == 9) {
    if (idx < 16 * 128) {
      int o = idx >> 7, k = idx & 127;
      float v = 0.f;
      if (o < 5) v = Wt[k * 5 + o];
      else if (o < 9) v = Wi[k * 4 + (o - 5)];
      else if (o < 12) v = Wm[k * 3 + (o - 9)];
      Wht[o * 128 + k] = f2bf(v);
    }
    return;
  }
  int K = (y < 2) ? 256 : 128;
  if (idx >= K * 128) return;
  int k = idx >> 7, n = idx & 127;
  float v;
  unsigned short* out;
  switch (y) {
    case 0: v = c1s_Wl[idx]; out = Bt_c1s; break;
    case 1: v = c1s_Wr[idx] + c1a_Wr[idx] + c1t_Wr[idx]; out = Bt_W1s; break;
    case 2: v = c1a_Wl[idx]; out = Bt_c1a; break;
    case 3: v = c1t_Wl[idx]; out = Bt_c1t; break;
    case 4: v = c2s_Wl[idx]; out = Bt_c2s; break;
    case 5: v = c2s_Wr[idx] + c2a_Wr[idx] + c2t_Wr[idx]; out = Bt_W2s; break;
    case 6: v = c2a_Wl[idx]; out = Bt_c2a; break;
    default: v = c2t_Wl[idx]; out = Bt_c2t; break;
  }
  out[n * K + k] = f2bf(v);
}

// ------------------------------------------------------------------
// MFMA GEMM: C0(bf16) = act(A)@B0 [, C1(fp32) = act(A)@B1 + bias1]
// tile 128x128, 4 waves 2x2, BK=64, mfma 16x16x32 bf16
// A/C1 not __restrict__ — layer-2 call runs in-place (C1 == A).
// ------------------------------------------------------------------
template <int KD, bool DUAL, bool RELUA>
__global__ __launch_bounds__(256, 2) void mfma_gemm(
    const float* A, int M,
    const unsigned short* __restrict__ B0t, const unsigned short* __restrict__ B1t,
    unsigned short* __restrict__ C0, float* C1, const float* __restrict__ bias1) {
  constexpr int AST = 72;
  __shared__ unsigned short As[128 * AST];
  __shared__ unsigned short Bs0[128 * AST];
  __shared__ unsigned short Bs1[DUAL ? 128 * AST : 8];

  const int t = threadIdx.x;
  const int wave = t >> 6, lane = t & 63;
  const int wm = (wave & 1) * 64;
  const int wn = (wave >> 1) * 64;
  const int m0 = blockIdx.x * 128;
  const int lrow = lane & 15, lq = lane >> 4;

  v4f acc0[4][4];
  v4f acc1[DUAL ? 4 : 1][DUAL ? 4 : 1];
#pragma unroll
  for (int i = 0; i < 4; ++i)
#pragma unroll
    for (int j = 0; j < 4; ++j) acc0[i][j] = (v4f)(0.f);
  if constexpr (DUAL) {
#pragma unroll
    for (int i = 0; i < 4; ++i)
#pragma unroll
      for (int j = 0; j < 4; ++j) acc1[i][j] = (v4f)(0.f);
  }

  for (int k0 = 0; k0 < KD; k0 += 64) {
#pragma unroll
    for (int j = 0; j < 8; ++j) {
      int idx = j * 256 + t;
      int row = idx >> 4;
      int c4 = idx & 15;
      int gr = m0 + row;
      float4 v = make_float4(0.f, 0.f, 0.f, 0.f);
      if (gr < M) v = *(const float4*)(A + (size_t)gr * KD + k0 + c4 * 4);
      if (RELUA) {
        v.x = fmaxf(v.x, 0.f); v.y = fmaxf(v.y, 0.f);
        v.z = fmaxf(v.z, 0.f); v.w = fmaxf(v.w, 0.f);
      }
      unsigned short* d = &As[row * AST + c4 * 4];
      d[0] = f2bf(v.x); d[1] = f2bf(v.y); d[2] = f2bf(v.z); d[3] = f2bf(v.w);
    }
#pragma unroll
    for (int j = 0; j < 4; ++j) {
      int idx = j * 256 + t;
      int row = idx >> 3;
      int k8 = idx & 7;
      uint4 v = *(const uint4*)(B0t + (size_t)row * KD + k0 + k8 * 8);
      *(uint4*)&Bs0[row * AST + k8 * 8] = v;
      if constexpr (DUAL) {
        uint4 w = *(const uint4*)(B1t + (size_t)row * KD + k0 + k8 * 8);
        *(uint4*)&Bs1[row * AST + k8 * 8] = w;
      }
    }
    __syncthreads();

#pragma unroll
    for (int ks = 0; ks < 2; ++ks) {
      v8s af[4];
#pragma unroll
      for (int mt = 0; mt < 4; ++mt)
        af[mt] = *(const v8s*)&As[(wm + mt * 16 + lrow) * AST + ks * 32 + lq * 8];
#pragma unroll
      for (int cb = 0; cb < 4; ++cb) {
        v8s b0 = *(const v8s*)&Bs0[(wn + cb * 16 + lrow) * AST + ks * 32 + lq * 8];
#pragma unroll
        for (int mt = 0; mt < 4; ++mt)
          acc0[mt][cb] = __builtin_amdgcn_mfma_f32_16x16x32_bf16(af[mt], b0, acc0[mt][cb], 0, 0, 0);
        if constexpr (DUAL) {
          v8s b1 = *(const v8s*)&Bs1[(wn + cb * 16 + lrow) * AST + ks * 32 + lq * 8];
#pragma unroll
          for (int mt = 0; mt < 4; ++mt)
            acc1[mt][cb] = __builtin_amdgcn_mfma_f32_16x16x32_bf16(af[mt], b1, acc1[mt][cb], 0, 0, 0);
        }
      }
    }
    __syncthreads();
  }

  float bv[4] = {0.f, 0.f, 0.f, 0.f};
  if constexpr (DUAL) {
#pragma unroll
    for (int cb = 0; cb < 4; ++cb) bv[cb] = bias1[wn + cb * 16 + lrow];
  }
#pragma unroll
  for (int mt = 0; mt < 4; ++mt) {
#pragma unroll
    for (int r = 0; r < 4; ++r) {
      int gr = m0 + wm + mt * 16 + lq * 4 + r;
      if (gr < M) {
#pragma unroll
        for (int cb = 0; cb < 4; ++cb) {
          int gc = wn + cb * 16 + lrow;
          C0[(size_t)gr * 128 + gc] = f2bf(acc0[mt][cb][r]);
          if constexpr (DUAL) C1[(size_t)gr * 128 + gc] = acc1[mt][cb][r] + bv[cb];
        }
      }
    }
  }
}

// ------------------------------------------------------------------
// fused CSR gather, quarter-wave per edge
// ------------------------------------------------------------------
__global__ __launch_bounds__(256) void gather_kernel(
    const unsigned short* __restrict__ ys, const unsigned short* __restrict__ ya,
    const unsigned short* __restrict__ yt,
    const int* __restrict__ rs_all,
    const int* __restrict__ src_s, const int* __restrict__ src_a,
    const int* __restrict__ src_t,
    const float* __restrict__ inv, float* h, int M) {
  int row = blockIdx.x * 4 + (threadIdx.x >> 6);
  if (row >= M) return;
  const int lane = threadIdx.x & 63;
  const int q = lane >> 4;
  const int col = (lane & 15) * 8;
  const int NP = M + 1;

  int b0 = rs_all[row],          e0 = rs_all[row + 1];
  int b1 = rs_all[NP + row],     e1 = rs_all[NP + row + 1];
  int b2 = rs_all[2 * NP + row], e2 = rs_all[2 * NP + row + 1];
  float sc0 = inv[row], sc1 = inv[M + row], sc2 = inv[2 * M + row];

  float acc[8];
#pragma unroll
  for (int j = 0; j < 8; ++j) acc[j] = 0.f;

  auto seg = [&](const unsigned short* __restrict__ y, const int* __restrict__ src,
                 int b, int e, float sc) {
    float s[8];
#pragma unroll
    for (int j = 0; j < 8; ++j) s[j] = 0.f;
    for (int i = b + q; i < e; i += 4) {
      int si = src[i];
      uint4 v = *(const uint4*)(y + (size_t)si * HD + col);
      s[0] += __uint_as_float(v.x << 16);
      s[1] += __uint_as_float(v.x & 0xffff0000u);
      s[2] += __uint_as_float(v.y << 16);
      s[3] += __uint_as_float(v.y & 0xffff0000u);
      s[4] += __uint_as_float(v.z << 16);
      s[5] += __uint_as_float(v.z & 0xffff0000u);
      s[6] += __uint_as_float(v.w << 16);
      s[7] += __uint_as_float(v.w & 0xffff0000u);
    }
#pragma unroll
    for (int j = 0; j < 8; ++j) acc[j] += s[j] * sc;
  };
  seg(ys, src_s, b0, e0, sc0);
  seg(ya, src_a, b1, e1, sc1);
  seg(yt, src_t, b2, e2, sc2);

#pragma unroll
  for (int j = 0; j < 8; ++j) {
    acc[j] += __shfl_xor(acc[j], 16);
    acc[j] += __shfl_xor(acc[j], 32);
  }
  if (q == 0) {
    float4* hp = (float4*)(h + (size_t)row * HD + col);
    float4 a = hp[0], b = hp[1];
    a.x += acc[0]; a.y += acc[1]; a.z += acc[2]; a.w += acc[3];
    b.x += acc[4]; b.y += acc[5]; b.z += acc[6]; b.w += acc[7];
    hp[0] = a; hp[1] = b;
  }
}

// ------------------------------------------------------------------
// heads pass 1: P[M x 16] = relu(h2) @ Wht^T + bh  (MFMA 16x16x32 bf16)
// 64 rows per block (4 waves x 16 rows), single LDS staging, no k-barrier
// AST_H = 136: full 128-col row + 8-short pad (16B-aligned row stride;
// 68-dword stride -> 2-way bank aliasing = free). 64*136*2 = 17.4 KB LDS.
// ------------------------------------------------------------------
__global__ __launch_bounds__(256, 4) void heads_gemm(
    const float* __restrict__ h2, int M,
    const unsigned short* __restrict__ Wht, const float* __restrict__ bh,
    float* __restrict__ P) {
  constexpr int AST_H = 136;
  __shared__ unsigned short As[64 * AST_H];
  const int t = threadIdx.x;
  const int wave = t >> 6, lane = t & 63;
  const int m0 = blockIdx.x * 64;
  const int lrow = lane & 15, lq = lane >> 4;

#pragma unroll
  for (int j = 0; j < 8; ++j) {
    int idx = j * 256 + t;       // 2048 float4 slots = 64 rows x 32
    int row = idx >> 5;
    int c4 = idx & 31;
    int gr = m0 + row;
    float4 v = make_float4(0.f, 0.f, 0.f, 0.f);
    if (gr < M) v = *(const float4*)(h2 + (size_t)gr * 128 + c4 * 4);
    v.x = fmaxf(v.x, 0.f); v.y = fmaxf(v.y, 0.f);
    v.z = fmaxf(v.z, 0.f); v.w = fmaxf(v.w, 0.f);
    unsigned short* d = &As[row * AST_H + c4 * 4];
    d[0] = f2bf(v.x); d[1] = f2bf(v.y); d[2] = f2bf(v.z); d[3] = f2bf(v.w);
  }
  __syncthreads();

  v4f acc = (v4f)(0.f);
#pragma unroll
  for (int ks = 0; ks < 4; ++ks) {
    v8s a = *(const v8s*)&As[(wave * 16 + lrow) * AST_H + ks * 32 + lq * 8];
    v8s b = *(const v8s*)(Wht + lrow * 128 + ks * 32 + lq * 8);
    acc = __builtin_amdgcn_mfma_f32_16x16x32_bf16(a, b, acc, 0, 0, 0);
  }
  float bv = bh[lrow];
#pragma unroll
  for (int r = 0; r < 4; ++r) {
    int gr = m0 + wave * 16 + lq * 4 + r;
    if (gr < M) P[(size_t)gr * 16 + lrow] = acc[r] + bv;
  }
}

// ------------------------------------------------------------------
// heads pass 2: thread-per-row sigmoid/softmax + impl head, scatter out
// ------------------------------------------------------------------
__global__ __launch_bounds__(256) void heads_epi(
    const float* __restrict__ P, const float* __restrict__ Wm,
    float* __restrict__ out_t, float* __restrict__ out_i,
    float* __restrict__ out_m, int M) {
  int row = blockIdx.x * 256 + threadIdx.x;
  if (row >= M) return;
  float4 p0 = *(const float4*)(P + (size_t)row * 16);
  float4 p1 = *(const float4*)(P + (size_t)row * 16 + 4);
  float4 p2 = *(const float4*)(P + (size_t)row * 16 + 8);
  float t_[5] = {p0.x, p0.y, p0.z, p0.w, p1.x};
  float i_[4] = {p1.y, p1.z, p1.w, p2.x};
  float mb[3] = {p2.y, p2.z, p2.w};
  float tp[5];
#pragma unroll
  for (int o = 0; o < 5; ++o) tp[o] = 1.f / (1.f + __expf(-t_[o]));
  float mx = fmaxf(fmaxf(i_[0], i_[1]), fmaxf(i_[2], i_[3]));
  float ex[4], es = 0.f;
#pragma unroll
  for (int o = 0; o < 4; ++o) { ex[o] = __expf(i_[o] - mx); es += ex[o]; }
  float inv_es = 1.f / es;
  float ml[3];
#pragma unroll
  for (int o = 0; o < 3; ++o) {
    float v = mb[o];
#pragma unroll
    for (int j = 0; j < 5; ++j) v += tp[j] * Wm[(128 + j) * 3 + o];
#pragma unroll
    for (int j = 0; j < 4; ++j) v += (ex[j] * inv_es) * Wm[(133 + j) * 3 + o];
    ml[o] = v;
  }
#pragma unroll
  for (int o = 0; o < 5; ++o) out_t[(size_t)row * 5 + o] = t_[o];
#pragma unroll
  for (int o = 0; o < 4; ++o) out_i[(size_t)row * 4 + o] = i_[o];
#pragma unroll
  for (int o = 0; o < 3; ++o) out_m[(size_t)row * 3 + o] = ml[o];
}

// ------------------------------------------------------------------
extern "C" void kernel_launch(void* const* d_in, const int* in_sizes, int n_in,
                              void* d_out, int out_size, void* d_ws, size_t ws_size,
                              hipStream_t stream) {
  const float* x_comment = (const float*)d_in[0];
  const float* x_topic   = (const float*)d_in[1];
  const float* x_claim   = (const float*)d_in[2];
  const float* c1s_Wl = (const float*)d_in[3];
  const float* c1s_bl = (const float*)d_in[4];
  const float* c1s_Wr = (const float*)d_in[5];
  const float* c1a_Wl = (const float*)d_in[6];
  const float* c1a_bl = (const float*)d_in[7];
  const float* c1a_Wr = (const float*)d_in[8];
  const float* c1t_Wl = (const float*)d_in[9];
  const float* c1t_bl = (const float*)d_in[10];
  const float* c1t_Wr = (const float*)d_in[11];
  const float* c2s_Wl = (const float*)d_in[12];
  const float* c2s_bl = (const float*)d_in[13];
  const float* c2s_Wr = (const float*)d_in[14];
  const float* c2a_Wl = (const float*)d_in[15];
  const float* c2a_bl = (const float*)d_in[16];
  const float* c2a_Wr = (const float*)d_in[17];
  const float* c2t_Wl = (const float*)d_in[18];
  const float* c2t_bl = (const float*)d_in[19];
  const float* c2t_Wr = (const float*)d_in[20];
  const float* Wt = (const float*)d_in[21];
  const float* bt = (const float*)d_in[22];
  const float* Wi = (const float*)d_in[23];
  const float* bi = (const float*)d_in[24];
  const float* Wm = (const float*)d_in[25];
  const float* bm = (const float*)d_in[26];
  const int* ei_sim = (const int*)d_in[27];
  const int* ei_ab  = (const int*)d_in[28];
  const int* ei_tg  = (const int*)d_in[29];

  const int E_sim = in_sizes[27] / 2;
  const int E_ab  = in_sizes[28] / 2;
  const int E_tg  = in_sizes[29] / 2;
  const int N_T = in_sizes[1] / 128;
  const int N_CL = in_sizes[2] / 128;

  float* ws = (float*)d_ws;
  // workspace (float-element offsets)
  float* h1 = ws;                                          // 12.8M fp32
  unsigned short* y_s = (unsigned short*)(ws + 12800000);  // 100000*128 bf16
  unsigned short* y_a = (unsigned short*)(ws + 19200000);  // 5000*128 bf16
  unsigned short* y_t = (unsigned short*)(ws + 19520000);  // 20000*128 bf16
  int*   cnt    = (int*)(ws + 20800000);                   // 3*N_C
  float* inv    = ws + 21100000;                           // 3*N_C
  int*   rs_all = (int*)(ws + 21400000);                   // 3*(N_C+1)
  int*   src_s  = (int*)(ws + 21700016);                   // E_sim
  int*   src_a  = (int*)(ws + 22300016);                   // E_ab
  int*   src_t  = (int*)(ws + 22600016);                   // E_tg
  int*   part   = (int*)(ws + 22900016);                   // 3*128
  float* b1s    = ws + 22900416;
  float* b2s    = ws + 22900544;
  unsigned short* Bt_c1s = (unsigned short*)(ws + 22900672);  // 128x256
  unsigned short* Bt_W1s = Bt_c1s + 32768;                    // 128x256
  unsigned short* Bt_c1a = Bt_W1s + 32768;                    // 128x128
  unsigned short* Bt_c1t = Bt_c1a + 16384;
  unsigned short* Bt_c2s = Bt_c1t + 16384;
  unsigned short* Bt_W2s = Bt_c2s + 16384;
  unsigned short* Bt_c2a = Bt_W2s + 16384;
  unsigned short* Bt_c2t = Bt_c2a + 16384;                    // ends at float 22982592
  float* P      = ws + 23000000;                              // 100000*16 fp32
  unsigned short* Wht = (unsigned short*)(ws + 24600000);     // 16x128 bf16
  float* bh     = ws + 24601100;                              // 16

  const int nbS = (N_C + SCAN_CHUNK - 1) / SCAN_CHUNK;
  const int ebx = (E_sim + 255) / 256;

  // ---- weight prep ----
  prep_weights<<<dim3(128, 10), 256, 0, stream>>>(
      c1s_Wl, c1s_Wr, c1a_Wr, c1t_Wr, c1a_Wl, c1t_Wl,
      c2s_Wl, c2s_Wr, c2a_Wr, c2t_Wr, c2a_Wl, c2t_Wl,
      c1s_bl, c1a_bl, c1t_bl, c2s_bl, c2a_bl, c2t_bl,
      Wt, bt, Wi, bi, Wm, bm,
      Bt_c1s, Bt_W1s, Bt_c1a, Bt_c1t, Bt_c2s, Bt_W2s, Bt_c2a, Bt_c2t,
      Wht, b1s, b2s, bh);

  // ---- degree histogram + CSR build ----
  hipMemsetAsync(cnt, 0, 3 * N_C * sizeof(int), stream);
  count3_kernel<<<dim3(ebx, 3), 256, 0, stream>>>(ei_sim, E_sim, ei_ab, E_ab, ei_tg, E_tg, cnt);
  scan_phaseA<<<dim3(nbS, 3), 256, 0, stream>>>(cnt, part, inv, N_C);
  scan_phaseB<<<dim3(1, 3), 256, 0, stream>>>(part, nbS);
  scan_phaseC<<<dim3(nbS, 3), 256, 0, stream>>>(cnt, part, rs_all, N_C);
  set_totals<<<1, 64, 0, stream>>>(rs_all, E_sim, E_ab, E_tg, N_C);
  hipMemsetAsync(cnt, 0, 3 * N_C * sizeof(int), stream);
  place3_kernel<<<dim3(ebx, 3), 256, 0, stream>>>(
      ei_sim, E_sim, ei_ab, E_ab, ei_tg, E_tg, rs_all, cnt, src_s, src_a, src_t, N_C);

  // ---------------- layer 1 ----------------
  mfma_gemm<256, true, false><<<(N_C + 127) / 128, 256, 0, stream>>>(
      x_comment, N_C, Bt_c1s, Bt_W1s, y_s, h1, b1s);
  mfma_gemm<128, false, false><<<(N_T + 127) / 128, 256, 0, stream>>>(
      x_topic, N_T, Bt_c1a, nullptr, y_a, nullptr, nullptr);
  mfma_gemm<128, false, false><<<(N_CL + 127) / 128, 256, 0, stream>>>(
      x_claim, N_CL, Bt_c1t, nullptr, y_t, nullptr, nullptr);

  gather_kernel<<<(N_C + 3) / 4, 256, 0, stream>>>(
      y_s, y_a, y_t, rs_all, src_s, src_a, src_t, inv, h1, N_C);

  // ---------------- layer 2 (in-place h1 -> h2) ----------------
  mfma_gemm<128, true, true><<<(N_C + 127) / 128, 256, 0, stream>>>(
      h1, N_C, Bt_c2s, Bt_W2s, y_s, h1, b2s);
  mfma_gemm<128, false, false><<<(N_T + 127) / 128, 256, 0, stream>>>(
      x_topic, N_T, Bt_c2a, nullptr, y_a, nullptr, nullptr);
  mfma_gemm<128, false, false><<<(N_CL + 127) / 128, 256, 0, stream>>>(
      x_claim, N_CL, Bt_c2t, nullptr, y_t, nullptr, nullptr);

  gather_kernel<<<(N_C + 3) / 4, 256, 0, stream>>>(
      y_s, y_a, y_t, rs_all, src_s, src_a, src_t, inv, h1, N_C);

  // ---------------- heads ----------------
  float* out = (float*)d_out;
  heads_gemm<<<(N_C + 63) / 64, 256, 0, stream>>>(h1, N_C, Wht, bh, P);
  heads_epi<<<(N_C + 255) / 256, 256, 0, stream>>>(
      P, Wm, out, out + (size_t)N_C * 5, out + (size_t)N_C * 9, N_C);
}